// Round 7
// baseline (478.033 us; speedup 1.0000x reference)
//
#include <hip/hip_runtime.h>
#include <cstdint>
#include <cstddef>

typedef unsigned short u16;
typedef __bf16 bf16x8 __attribute__((ext_vector_type(8)));
typedef float f32x4 __attribute__((ext_vector_type(4)));
typedef unsigned int u32;
typedef u32 u32x4 __attribute__((ext_vector_type(4)));
typedef u16 u16x8 __attribute__((ext_vector_type(8)));
typedef u16 u16x4 __attribute__((ext_vector_type(4)));

#define MFMA16(a, b, c) __builtin_amdgcn_mfma_f32_16x16x32_bf16((a), (b), (c), 0, 0, 0)

static constexpr int B = 32, T = 512, D = 500, H = 10, HD = 50;
static constexpr int M = B * T;          // 16384 tokens

__device__ __forceinline__ float b2f(u16 u) { return (float)__builtin_bit_cast(__bf16, u); }
__device__ __forceinline__ u16 f2b(float f) { return __builtin_bit_cast(u16, (__bf16)f); }

__device__ __forceinline__ void async16(const void* g, void* s) {
  __builtin_amdgcn_global_load_lds((const __attribute__((address_space(1))) void*)g,
                                   (__attribute__((address_space(3))) void*)s, 16, 0, 0);
}

// Counted waits for in-flight global_load_lds. vmcnt(N) waits until <=N VMEM ops
// remain outstanding; tile-(k+1)'s 4 loads are always the newest 4, so vmcnt(4)
// guarantees tile k landed while keeping k+1 in flight ACROSS the barrier (T4).
__device__ __forceinline__ void wait_vm4() {
  asm volatile("s_waitcnt vmcnt(4)" ::: "memory");
}
__device__ __forceinline__ void drain_vm() {
  asm volatile("s_waitcnt vmcnt(0)" ::: "memory");
}

// ---------------- all weight packing + PE table in ONE kernel ----------------
__global__ __launch_bounds__(256) void packall(
    const float* __restrict__ pw0, const float* __restrict__ pw1,
    const float* __restrict__ pw2, const float* __restrict__ pw3,
    const float* __restrict__ ow, const float* __restrict__ fw,
    const float* __restrict__ inw, const float* __restrict__ inb,
    u16* __restrict__ PW, u16* __restrict__ OW, u16* __restrict__ FW,
    u16* __restrict__ INW, float* __restrict__ INB, float* __restrict__ PE) {
  int bx = blockIdx.x;
  if (bx < 3072) {
    int which = bx >> 9, o = bx & 511;
    const float* src = which == 0 ? pw0 : which == 1 ? pw1 : which == 2 ? pw2
                     : which == 3 ? pw3 : which == 4 ? ow : fw;
    u16* dst = which < 4 ? PW + (size_t)which * 512 * 512 : (which == 4 ? OW : FW);
    for (int c = threadIdx.x; c < 512; c += 256)
      dst[o * 512 + c] = (o < 500 && c < 500) ? f2b(src[o * 500 + c]) : (u16)0;
    return;
  }
  bx -= 3072;
  if (bx < 1536) {
    int e = bx;
    for (int c = threadIdx.x; c < 512; c += 256) {
      u16 v = 0;
      if (e < 1500 && c < 500) {
        float f = inw[e * 500 + c];
        if (e < 500) f *= 0.14142135623730951f;
        v = f2b(f);
      }
      INW[e * 512 + c] = v;
    }
    return;
  }
  bx -= 1536;
  if (bx < 512) {
    int t = bx;
    float fp = (float)(t + 1);
    for (int d = threadIdx.x; d < 512; d += 256) {
      float pe = 0.f;
      if (d < 500) {
        int i = (d < 250) ? d : d - 250;
        float ang = fp * expf((float)i * -0.036989318762956f); // -ln(10000)/249
        pe = (d < 250) ? sinf(ang) : cosf(ang);
      }
      PE[t * 512 + d] = pe;
    }
    return;
  }
  bx -= 512;
  int e = bx * 256 + threadIdx.x;
  if (e < 1536) {
    float f = 0.f;
    if (e < 1500) {
      f = inb[e];
      if (e < 500) f *= 0.14142135623730951f;
    }
    INB[e] = f;
  }
}

// ---------------- positional embedding + add (table lookup, no trig) ----------------
__global__ __launch_bounds__(256) void posemb(const int* __restrict__ ori, const float* __restrict__ x,
                                              const float* __restrict__ PE, u16* __restrict__ out) {
  int m = blockIdx.x;
  int t = m & 511;
  bool np = (ori[m] != 0);
  for (int d = threadIdx.x; d < 512; d += 256) {
    float v = 0.f;
    if (d < 500) {
      float pe = np ? PE[t * 512 + d] : 0.f;
      v = pe + x[(size_t)m * 500 + d];
    }
    out[(size_t)m * 512 + d] = f2b(v);
  }
}

// ---------------- depthwise conv (k=7, pad=3) along T ----------------
// Sliding-window register staging: each thread owns 4 channels (u16x4) and 4
// CONSECUTIVE t-values, so a 10-row window (10 independent 8 B loads, issued
// upfront -> single latency wait) covers all 4 outputs.
__global__ __launch_bounds__(256) void dwconv(const u16* __restrict__ X, const float* __restrict__ dw,
                                              const float* __restrict__ db, u16* __restrict__ Y) {
  int b = blockIdx.y;
  int t0 = blockIdx.x * 8;
  int c0 = (threadIdx.x & 127) * 4;  // channel base (0..508)
  int ts = threadIdx.x >> 7;         // 0..1
  int tb = t0 + ts * 4;              // first output t (consecutive 4)

  float wv[7][4];
  float bias[4];
#pragma unroll
  for (int j = 0; j < 4; j++) {
    int c = c0 + j;
    bool ok = (c < 500);
    bias[j] = ok ? db[c] : 0.f;
#pragma unroll
    for (int k = 0; k < 7; k++) wv[k][j] = ok ? dw[c * 7 + k] : 0.f;
  }

  const u16* Xb = X + (size_t)b * 512 * 512 + c0;
  u16* Yb = Y + (size_t)b * 512 * 512 + c0;

  u16x4 xr[10];
#pragma unroll
  for (int k = 0; k < 10; k++) {
    int tt = tb - 3 + k;
    u16x4 z = {0, 0, 0, 0};
    xr[k] = (tt >= 0 && tt < 512) ? *(const u16x4*)(Xb + (size_t)tt * 512) : z;
  }

#pragma unroll
  for (int it = 0; it < 4; it++) {
    float acc[4] = {bias[0], bias[1], bias[2], bias[3]};
#pragma unroll
    for (int k = 0; k < 7; k++)
#pragma unroll
      for (int j = 0; j < 4; j++)
        acc[j] += wv[k][j] * b2f(xr[it + k][j]);
    u16x4 o;
#pragma unroll
    for (int j = 0; j < 4; j++) o[j] = f2b(acc[j]);
    *(u16x4*)(Yb + (size_t)(tb + it) * 512) = o;
  }
}

// ---------------- GEMM: out[m][n] = sum_k A[m][k]*W[n][k] + bias + res ----------------
// 3-buffer K-loop with counted vmcnt (depth-2 prefetch): per iter
// {vmcnt(4) -> barrier -> STAGE(kk+2) -> COMPUTE(kk)}.
// Epilogue: f32 tile staged in LDS (two 64-row halves), coalesced u16x8 res/store.
__global__ __launch_bounds__(256) void gemm_bt(const u16* __restrict__ A, const u16* __restrict__ W,
                                               const float* __restrict__ bias, int nbias,
                                               const u16* __restrict__ res,
                                               u16* __restrict__ outb, float* __restrict__ outf,
                                               int ldo, int nstore) {
  union SM {
    struct { u16 A[3][4096]; u16 B[3][4096]; } s;  // 48 KB staging (triple-buffered)
    float o[64 * 132];                             // 33.8 KB epilogue half-tile (pad 132: 2-way-free)
  };
  __shared__ __align__(16) SM sm;

  int tid = threadIdx.x;
  int m0 = blockIdx.x * 128;
  int n0 = blockIdx.y * 128;
  int lane = tid & 63, w = tid >> 6;
  int wm = (w & 1) * 64, wn = (w >> 1) * 64;
  int lr = lane & 15, kg = lane >> 4;

  f32x4 acc[4][4] = {};
  int row = tid >> 2, sub = tid & 3;
  const u16* ga = A + (size_t)(m0 + row) * 512 + sub * 8;
  const u16* gb = W + (size_t)(n0 + row) * 512 + sub * 8;

  auto STAGE = [&](int buf, int kk) {
    const u16* ga0 = ga + kk * 32;
    const u16* gb0 = gb + kk * 32;
    async16(ga0, sm.s.A[buf] + tid * 8);
    async16(ga0 + 64 * 512, sm.s.A[buf] + 2048 + tid * 8);
    async16(gb0, sm.s.B[buf] + tid * 8);
    async16(gb0 + 64 * 512, sm.s.B[buf] + 2048 + tid * 8);
  };
  auto COMPUTE = [&](int buf) {
    bf16x8 af[4], bfr[4];
#pragma unroll
    for (int i = 0; i < 4; i++) af[i] = *(const bf16x8*)(sm.s.A[buf] + (wm + i * 16 + lr) * 32 + kg * 8);
#pragma unroll
    for (int j = 0; j < 4; j++) bfr[j] = *(const bf16x8*)(sm.s.B[buf] + (wn + j * 16 + lr) * 32 + kg * 8);
#pragma unroll
    for (int i = 0; i < 4; i++)
#pragma unroll
      for (int j = 0; j < 4; j++) acc[i][j] = MFMA16(af[i], bfr[j], acc[i][j]);
  };

  STAGE(0, 0);
  STAGE(1, 1);
#pragma unroll
  for (int kk = 0; kk < 16; kk++) {
    if (kk < 15) wait_vm4();       // tile kk landed; kk+1 stays in flight
    else         drain_vm();       // last tile: full drain
    __builtin_amdgcn_sched_barrier(0);
    __syncthreads();               // all waves' tile-kk loads visible; buf(kk-1) readers done
    if (kk + 2 < 16) STAGE((kk + 2) % 3, kk + 2);  // overwrites buf(kk-1)
    COMPUTE(kk % 3);
  }
  __syncthreads();                 // all ds_reads done before epilogue aliases LDS

  // ---- epilogue: two row-halves through LDS, coalesced global I/O ----
#pragma unroll
  for (int half = 0; half < 2; half++) {
    if ((w & 1) == half) {         // waves owning rows [half*64, half*64+64)
#pragma unroll
      for (int i = 0; i < 4; i++)
#pragma unroll
        for (int j = 0; j < 4; j++) {
          int gn = n0 + wn + j * 16 + lr;
          float bv = (gn < nbias) ? bias[gn] : 0.f;
#pragma unroll
          for (int r = 0; r < 4; r++)
            sm.o[(i * 16 + kg * 4 + r) * 132 + wn + j * 16 + lr] = acc[i][j][r] + bv;
        }
    }
    __syncthreads();
    int rl = tid >> 4;             // 0..15
    int colv = (tid & 15) * 8;     // 0..120, 16B-granular: lanes cover a contiguous 256B row span
#pragma unroll
    for (int p = 0; p < 4; p++) {
      int rrow = rl + p * 16;      // 0..63
      int m = m0 + half * 64 + rrow;
      const float* lp = sm.o + rrow * 132 + colv;
      f32x4 v0 = *(const f32x4*)lp;
      f32x4 v1 = *(const f32x4*)(lp + 4);
      if (res != nullptr) {
        u16x8 rv = *(const u16x8*)(res + (size_t)m * 512 + n0 + colv);
#pragma unroll
        for (int k = 0; k < 4; k++) { v0[k] += b2f(rv[k]); v1[k] += b2f(rv[4 + k]); }
      }
      if (outf != nullptr) {
        int gc = n0 + colv;
        if (gc + 4 <= nstore) *(f32x4*)(outf + (size_t)m * ldo + gc) = v0;
        if (gc + 8 <= nstore) *(f32x4*)(outf + (size_t)m * ldo + gc + 4) = v1;
      } else {
        u16x8 ov;
#pragma unroll
        for (int k = 0; k < 4; k++) { ov[k] = f2b(v0[k]); ov[4 + k] = f2b(v1[k]); }
        *(u16x8*)(outb + (size_t)m * ldo + n0 + colv) = ov;
      }
    }
    __syncthreads();
  }
}

// ---------------- QKV GEMM with head-separated scatter epilogue ----------------
// Full-batch: grid (128, 12); writes the full 60 MB QKV buffer (bl = global batch).
__global__ __launch_bounds__(256) void gemm_qkv(const u16* __restrict__ A, const u16* __restrict__ W,
                                                const float* __restrict__ bias, u16* __restrict__ out) {
  __shared__ __align__(16) u16 As[3][128 * 32];
  __shared__ __align__(16) u16 Bs[3][128 * 32];
  int tid = threadIdx.x;
  int m0 = blockIdx.x * 128;
  int n0 = blockIdx.y * 128;
  int lane = tid & 63, w = tid >> 6;
  int wm = (w & 1) * 64, wn = (w >> 1) * 64;
  int lr = lane & 15, kg = lane >> 4;

  f32x4 acc[4][4] = {};
  int row = tid >> 2, sub = tid & 3;
  const u16* ga = A + (size_t)(m0 + row) * 512 + sub * 8;
  const u16* gb = W + (size_t)(n0 + row) * 512 + sub * 8;

  auto STAGE = [&](int buf, int kk) {
    const u16* ga0 = ga + kk * 32;
    const u16* gb0 = gb + kk * 32;
    async16(ga0, As[buf] + tid * 8);
    async16(ga0 + 64 * 512, As[buf] + 2048 + tid * 8);
    async16(gb0, Bs[buf] + tid * 8);
    async16(gb0 + 64 * 512, Bs[buf] + 2048 + tid * 8);
  };
  auto COMPUTE = [&](int buf) {
    bf16x8 af[4], bfr[4];
#pragma unroll
    for (int i = 0; i < 4; i++) af[i] = *(const bf16x8*)(As[buf] + (wm + i * 16 + lr) * 32 + kg * 8);
#pragma unroll
    for (int j = 0; j < 4; j++) bfr[j] = *(const bf16x8*)(Bs[buf] + (wn + j * 16 + lr) * 32 + kg * 8);
#pragma unroll
    for (int i = 0; i < 4; i++)
#pragma unroll
      for (int j = 0; j < 4; j++) acc[i][j] = MFMA16(af[i], bfr[j], acc[i][j]);
  };

  STAGE(0, 0);
  STAGE(1, 1);
#pragma unroll
  for (int kk = 0; kk < 16; kk++) {
    if (kk < 15) wait_vm4();
    else         drain_vm();
    __builtin_amdgcn_sched_barrier(0);
    __syncthreads();
    if (kk + 2 < 16) STAGE((kk + 2) % 3, kk + 2);
    COMPUTE(kk % 3);
  }

#pragma unroll
  for (int i = 0; i < 4; i++) {
#pragma unroll
    for (int j = 0; j < 4; j++) {
      int n = n0 + wn + j * 16 + lr;
      if (n >= 1500) continue;
      int sel = n / 500;
      int rem = n - sel * 500;
      int head = rem / 50;
      int hd = rem - head * 50;
      float bv = bias[n];
#pragma unroll
      for (int r = 0; r < 4; r++) {
        int m = m0 + wm + i * 16 + kg * 4 + r;
        int bl = m >> 9, t = m & 511;
        size_t dst = ((size_t)(bl * 10 + head) * 3 + sel) * 32768 +
                     (sel < 2 ? (t * 64 + hd) : (hd * 512 + t));
        out[dst] = f2b(acc[i][j][r] + bv);
      }
    }
  }
}

// ---------------- fused attention (flash-style, online softmax) ----------------
// Flat grid 2560 with XCD-aware decode (T1): the 8 qt-sibling blocks of one
// (b,h) share bx%8 (same XCD) and are 8 apart in linear id (dispatched nearly
// simultaneously) -> they consume the same K/V stream while it is L2-hot,
// instead of each XCD fetching its own copy (FETCH was 2.9x the buffer size).
static constexpr int LP = 72;
__global__ __launch_bounds__(256) void attn(const u16* __restrict__ qkv, u16* __restrict__ att) {
  __shared__ __align__(16) u16 Qs[64 * LP];
  __shared__ __align__(16) u16 Ks[64 * LP];
  __shared__ __align__(16) u16 Vs[64 * LP];  // Vt[hd][t-within-tile]
  __shared__ __align__(16) u16 Ps[64 * LP];
  int tid = threadIdx.x;
  int bx = blockIdx.x;
  int r = bx & 7, s = bx >> 3;     // XCD residue, per-XCD sequence
  int qt = s & 7;                  // 8 siblings (qt 0..7) of one (b,h): same r, s consecutive
  int bh = (s >> 3) * 8 + r;       // 0..319, bijective over bx in [0,2560)
  int h = bh % 10, b = bh / 10;
  const u16* baseQ = qkv + ((size_t)(b * 10 + h) * 3 + 0) * 32768;
  const u16* baseK = baseQ + 32768;
  const u16* baseV = baseQ + 2 * 32768;

  int r0 = tid >> 3, cg = tid & 7;   // thread covers rows r0 and r0+32, col-group cg (8 u16)

  u32x4 kreg0, kreg1, vreg0, vreg1;
  auto LOADKV = [&](int kt) {
    const u16* pk = baseK + kt * 4096;
    const u16* pv = baseV + kt * 64;
    u32x4 z = {0, 0, 0, 0};
    kreg0 = (cg < 7) ? *(const u32x4*)(pk + r0 * 64 + cg * 8) : z;
    kreg1 = (cg < 7) ? *(const u32x4*)(pk + (r0 + 32) * 64 + cg * 8) : z;
    vreg0 = *(const u32x4*)(pv + (size_t)r0 * 512 + cg * 8);
    vreg1 = *(const u32x4*)(pv + (size_t)(r0 + 32) * 512 + cg * 8);
  };
  auto WRITEKV = [&]() {
    u32x4 k0 = kreg0, k1 = kreg1;
    if (cg == 6) { k0[1] = 0; k0[2] = 0; k0[3] = 0; k1[1] = 0; k1[2] = 0; k1[3] = 0; }
    *(u32x4*)(Ks + r0 * LP + cg * 8) = k0;
    *(u32x4*)(Ks + (r0 + 32) * LP + cg * 8) = k1;
    *(u32x4*)(Vs + r0 * LP + cg * 8) = vreg0;
    *(u32x4*)(Vs + (r0 + 32) * LP + cg * 8) = vreg1;
  };

  LOADKV(0);   // in flight during Q staging

  // stage Q tile with pad columns zeroed in the same pass
#pragma unroll
  for (int ii = 0; ii < 2; ii++) {
    int rr = r0 + ii * 32;
    u32x4 qv = {0, 0, 0, 0};
    if (cg < 7) qv = *(const u32x4*)(baseQ + qt * 4096 + rr * 64 + cg * 8);
    if (cg == 6) { qv[1] = 0; qv[2] = 0; qv[3] = 0; }
    *(u32x4*)(Qs + rr * LP + cg * 8) = qv;
  }
  __syncthreads();

  int lane = tid & 63, w = tid >> 6, lr = lane & 15, kg = lane >> 4;
  bf16x8 aq0 = *(const bf16x8*)(Qs + (w * 16 + lr) * LP + kg * 8);
  bf16x8 aq1 = *(const bf16x8*)(Qs + (w * 16 + lr) * LP + 32 + kg * 8);

  f32x4 O[4] = {};
  float mi[4], li[4];
#pragma unroll
  for (int i = 0; i < 4; i++) { mi[i] = -__builtin_inff(); li[i] = 0.f; }

  for (int kt = 0; kt < 8; kt++) {
    WRITEKV();                     // compiler inserts vmcnt wait on the staged regs
    if (kt < 7) LOADKV(kt + 1);    // issue next tile; flies during compute below
    __syncthreads();

    // S = Q K^T (each wave: its 16 q-rows x 64 k-cols)
    f32x4 sS[4];
#pragma unroll
    for (int j = 0; j < 4; j++) {
      bf16x8 bk0 = *(const bf16x8*)(Ks + (j * 16 + lr) * LP + kg * 8);
      bf16x8 bk1 = *(const bf16x8*)(Ks + (j * 16 + lr) * LP + 32 + kg * 8);
      f32x4 z = {0.f, 0.f, 0.f, 0.f};
      z = MFMA16(aq0, bk0, z);
      z = MFMA16(aq1, bk1, z);
      sS[j] = z;
    }

    // online softmax; C-layout: row = kg*4+rg, col = j*16+lr
#pragma unroll
    for (int rg = 0; rg < 4; rg++) {
      float mx = fmaxf(fmaxf(sS[0][rg], sS[1][rg]), fmaxf(sS[2][rg], sS[3][rg]));
      mx = fmaxf(mx, __shfl_xor(mx, 1));
      mx = fmaxf(mx, __shfl_xor(mx, 2));
      mx = fmaxf(mx, __shfl_xor(mx, 4));
      mx = fmaxf(mx, __shfl_xor(mx, 8));
      float mn = fmaxf(mi[rg], mx);
      float alpha = __expf(mi[rg] - mn);
      float rs = 0.f;
#pragma unroll
      for (int j = 0; j < 4; j++) {
        float p = __expf(sS[j][rg] - mn);
        sS[j][rg] = p;
        rs += p;
      }
      rs += __shfl_xor(rs, 1);
      rs += __shfl_xor(rs, 2);
      rs += __shfl_xor(rs, 4);
      rs += __shfl_xor(rs, 8);
      li[rg] = li[rg] * alpha + rs;
      mi[rg] = mn;
#pragma unroll
      for (int sb = 0; sb < 4; sb++) O[sb][rg] *= alpha;
#pragma unroll
      for (int j = 0; j < 4; j++)
        Ps[(w * 16 + kg * 4 + rg) * LP + j * 16 + lr] = f2b(sS[j][rg]);
    }

    // P (wave-private rows) -> A-frags; V^T rows as B operand
    bf16x8 ap0 = *(const bf16x8*)(Ps + (w * 16 + lr) * LP + kg * 8);
    bf16x8 ap1 = *(const bf16x8*)(Ps + (w * 16 + lr) * LP + 32 + kg * 8);
#pragma unroll
    for (int sb = 0; sb < 4; sb++) {
      bf16x8 bv0 = *(const bf16x8*)(Vs + (sb * 16 + lr) * LP + kg * 8);
      bf16x8 bv1 = *(const bf16x8*)(Vs + (sb * 16 + lr) * LP + 32 + kg * 8);
      O[sb] = MFMA16(ap0, bv0, O[sb]);
      O[sb] = MFMA16(ap1, bv1, O[sb]);
    }
    __syncthreads();               // Ks/Vs reads done before next WRITEKV
  }

#pragma unroll
  for (int rg = 0; rg < 4; rg++) {
    float inv = 1.f / li[rg];
    int t = qt * 64 + w * 16 + kg * 4 + rg;
    size_t rowbase = ((size_t)b * 512 + t) * 512;
#pragma unroll
    for (int sb = 0; sb < 4; sb++) {
      int hd = sb * 16 + lr;
      if (hd < 50)
        att[rowbase + h * 50 + hd] = f2b(O[sb][rg] * inv);
      else if (h == 9 && hd < 62)
        att[rowbase + 450 + hd] = 0;   // zero att pad cols 500..511
    }
  }
}

// ---------------- workspace layout (~114 MiB of the ~268 MiB ws) ----------------
static constexpr size_t MB = 1024 * 1024;
static constexpr size_t OFF_S0  = 0;                      // [0,16M)    x0 / out3 (bf16)
static constexpr size_t OFF_S1  = 16 * MB;                // [16M,32M)  ping-pong, then ATT
static constexpr size_t OFF_R   = 32 * MB;                // [32M,48M)  DW scratch -> OUT4
static constexpr size_t OFF_QKV = 48 * MB;                // [48M,108M) full head-separated QKV (60 MB)
static constexpr size_t OFF_PE  = 108 * MB;               // f32[512*512] (1 MB)
static constexpr size_t OFF_PW  = 109 * MB;
static constexpr size_t SZ_W = (size_t)512 * 512 * 2;
static constexpr size_t OFF_OW = OFF_PW + 4 * SZ_W;
static constexpr size_t OFF_FW = OFF_OW + SZ_W;
static constexpr size_t OFF_INW = OFF_FW + SZ_W;
static constexpr size_t OFF_INB = OFF_INW + (size_t)1536 * 512 * 2;   // f32[1536]

extern "C" void kernel_launch(void* const* d_in, const int* in_sizes, int n_in,
                              void* d_out, int out_size, void* d_ws, size_t ws_size,
                              hipStream_t stream) {
  const int* ori = (const int*)d_in[0];
  const float* x = (const float*)d_in[1];
  const float* dwv[4] = {(const float*)d_in[3], (const float*)d_in[7], (const float*)d_in[11], (const float*)d_in[15]};
  const float* dbv[4] = {(const float*)d_in[4], (const float*)d_in[8], (const float*)d_in[12], (const float*)d_in[16]};
  const float* pwv[4] = {(const float*)d_in[5], (const float*)d_in[9], (const float*)d_in[13], (const float*)d_in[17]};
  const float* pbv[4] = {(const float*)d_in[6], (const float*)d_in[10], (const float*)d_in[14], (const float*)d_in[18]};
  const float* in_w = (const float*)d_in[19];
  const float* in_b = (const float*)d_in[20];
  const float* out_w = (const float*)d_in[21];
  const float* out_b = (const float*)d_in[22];
  const float* ffc_w = (const float*)d_in[23];
  const float* ffc_b = (const float*)d_in[24];

  char* ws = (char*)d_ws;
  u16* S0  = (u16*)(ws + OFF_S0);
  u16* S1  = (u16*)(ws + OFF_S1);
  u16* R   = (u16*)(ws + OFF_R);
  u16* QKV = (u16*)(ws + OFF_QKV);
  float* PE = (float*)(ws + OFF_PE);
  u16* PW  = (u16*)(ws + OFF_PW);
  u16* OW  = (u16*)(ws + OFF_OW);
  u16* FW  = (u16*)(ws + OFF_FW);
  u16* INW = (u16*)(ws + OFF_INW);
  float* INB = (float*)(ws + OFF_INB);

  // all weight packing + PE table in one launch
  packall<<<5126, 256, 0, stream>>>(pwv[0], pwv[1], pwv[2], pwv[3], out_w, ffc_w, in_w, in_b,
                                    PW, OW, FW, INW, INB, PE);

  // x0 = pos_emb + x (table lookup)
  posemb<<<M, 256, 0, stream>>>(ori, x, PE, S0);

  // 4x sepconv + residual (DW scratch in R)
  u16* cur = S0;
  u16* nxt = S1;
  for (int i = 0; i < 4; i++) {
    dwconv<<<dim3(64, 32), 256, 0, stream>>>(cur, dwv[i], dbv[i], R);
    gemm_bt<<<dim3(128, 4), 256, 0, stream>>>(R, PW + (size_t)i * 512 * 512, pbv[i], 500,
                                              cur, nxt, nullptr, 512, 512);
    u16* t2 = cur; cur = nxt; nxt = t2;
  }
  // cur == S0 holds out3; S1 free

  // qkv projection (full batch) + attention (full batch, XCD-aware grid); ATT = S1
  gemm_qkv<<<dim3(128, 12), 256, 0, stream>>>(cur, INW, INB, QKV);
  attn<<<dim3(2560), 256, 0, stream>>>(QKV, S1);

  // out_proj + residual(out3=S0) -> OUT4 in R
  gemm_bt<<<dim3(128, 4), 256, 0, stream>>>(S1, OW, out_b, 500, cur, R, nullptr, 512, 512);

  // ffc + residual(OUT4) -> d_out f32 [M][500]
  gemm_bt<<<dim3(128, 4), 256, 0, stream>>>(R, FW, ffc_b, 500, R, nullptr, (float*)d_out, 500, 500);
}

// Round 8
// 465.558 us; speedup vs baseline: 1.0268x; 1.0268x over previous
//
#include <hip/hip_runtime.h>
#include <cstdint>
#include <cstddef>

typedef unsigned short u16;
typedef __bf16 bf16x8 __attribute__((ext_vector_type(8)));
typedef float f32x4 __attribute__((ext_vector_type(4)));
typedef unsigned int u32;
typedef u32 u32x4 __attribute__((ext_vector_type(4)));
typedef u16 u16x8 __attribute__((ext_vector_type(8)));
typedef u16 u16x4 __attribute__((ext_vector_type(4)));

#define MFMA16(a, b, c) __builtin_amdgcn_mfma_f32_16x16x32_bf16((a), (b), (c), 0, 0, 0)

static constexpr int B = 32, T = 512, D = 500, H = 10, HD = 50;
static constexpr int M = B * T;          // 16384 tokens

__device__ __forceinline__ float b2f(u16 u) { return (float)__builtin_bit_cast(__bf16, u); }
__device__ __forceinline__ u16 f2b(float f) { return __builtin_bit_cast(u16, (__bf16)f); }

__device__ __forceinline__ void async16(const void* g, void* s) {
  __builtin_amdgcn_global_load_lds((const __attribute__((address_space(1))) void*)g,
                                   (__attribute__((address_space(3))) void*)s, 16, 0, 0);
}

__device__ __forceinline__ void wait_vm4() {
  asm volatile("s_waitcnt vmcnt(4)" ::: "memory");
}
__device__ __forceinline__ void drain_vm() {
  asm volatile("s_waitcnt vmcnt(0)" ::: "memory");
}

// ---------------- all weight packing + PE table in ONE kernel ----------------
__global__ __launch_bounds__(256) void packall(
    const float* __restrict__ pw0, const float* __restrict__ pw1,
    const float* __restrict__ pw2, const float* __restrict__ pw3,
    const float* __restrict__ ow, const float* __restrict__ fw,
    const float* __restrict__ inw, const float* __restrict__ inb,
    u16* __restrict__ PW, u16* __restrict__ OW, u16* __restrict__ FW,
    u16* __restrict__ INW, float* __restrict__ INB, float* __restrict__ PE) {
  int bx = blockIdx.x;
  if (bx < 3072) {
    int which = bx >> 9, o = bx & 511;
    const float* src = which == 0 ? pw0 : which == 1 ? pw1 : which == 2 ? pw2
                     : which == 3 ? pw3 : which == 4 ? ow : fw;
    u16* dst = which < 4 ? PW + (size_t)which * 512 * 512 : (which == 4 ? OW : FW);
    for (int c = threadIdx.x; c < 512; c += 256)
      dst[o * 512 + c] = (o < 500 && c < 500) ? f2b(src[o * 500 + c]) : (u16)0;
    return;
  }
  bx -= 3072;
  if (bx < 1536) {
    int e = bx;
    for (int c = threadIdx.x; c < 512; c += 256) {
      u16 v = 0;
      if (e < 1500 && c < 500) {
        float f = inw[e * 500 + c];
        if (e < 500) f *= 0.14142135623730951f;
        v = f2b(f);
      }
      INW[e * 512 + c] = v;
    }
    return;
  }
  bx -= 1536;
  if (bx < 512) {
    int t = bx;
    float fp = (float)(t + 1);
    for (int d = threadIdx.x; d < 512; d += 256) {
      float pe = 0.f;
      if (d < 500) {
        int i = (d < 250) ? d : d - 250;
        float ang = fp * expf((float)i * -0.036989318762956f); // -ln(10000)/249
        pe = (d < 250) ? sinf(ang) : cosf(ang);
      }
      PE[t * 512 + d] = pe;
    }
    return;
  }
  bx -= 512;
  int e = bx * 256 + threadIdx.x;
  if (e < 1536) {
    float f = 0.f;
    if (e < 1500) {
      f = inb[e];
      if (e < 500) f *= 0.14142135623730951f;
    }
    INB[e] = f;
  }
}

// ---------------- positional embedding + add (table lookup, no trig) ----------------
__global__ __launch_bounds__(256) void posemb(const int* __restrict__ ori, const float* __restrict__ x,
                                              const float* __restrict__ PE, u16* __restrict__ out) {
  int m = blockIdx.x;
  int t = m & 511;
  bool np = (ori[m] != 0);
  for (int d = threadIdx.x; d < 512; d += 256) {
    float v = 0.f;
    if (d < 500) {
      float pe = np ? PE[t * 512 + d] : 0.f;
      v = pe + x[(size_t)m * 500 + d];
    }
    out[(size_t)m * 512 + d] = f2b(v);
  }
}

// ---------------- depthwise conv (k=7, pad=3) along T ----------------
__global__ __launch_bounds__(256) void dwconv(const u16* __restrict__ X, const float* __restrict__ dw,
                                              const float* __restrict__ db, u16* __restrict__ Y) {
  int b = blockIdx.y;
  int t0 = blockIdx.x * 8;
  int c0 = (threadIdx.x & 127) * 4;  // channel base (0..508)
  int ts = threadIdx.x >> 7;         // 0..1
  int tb = t0 + ts * 4;              // first output t (consecutive 4)

  float wv[7][4];
  float bias[4];
#pragma unroll
  for (int j = 0; j < 4; j++) {
    int c = c0 + j;
    bool ok = (c < 500);
    bias[j] = ok ? db[c] : 0.f;
#pragma unroll
    for (int k = 0; k < 7; k++) wv[k][j] = ok ? dw[c * 7 + k] : 0.f;
  }

  const u16* Xb = X + (size_t)b * 512 * 512 + c0;
  u16* Yb = Y + (size_t)b * 512 * 512 + c0;

  u16x4 xr[10];
#pragma unroll
  for (int k = 0; k < 10; k++) {
    int tt = tb - 3 + k;
    u16x4 z = {0, 0, 0, 0};
    xr[k] = (tt >= 0 && tt < 512) ? *(const u16x4*)(Xb + (size_t)tt * 512) : z;
  }

#pragma unroll
  for (int it = 0; it < 4; it++) {
    float acc[4] = {bias[0], bias[1], bias[2], bias[3]};
#pragma unroll
    for (int k = 0; k < 7; k++)
#pragma unroll
      for (int j = 0; j < 4; j++)
        acc[j] += wv[k][j] * b2f(xr[it + k][j]);
    u16x4 o;
#pragma unroll
    for (int j = 0; j < 4; j++) o[j] = f2b(acc[j]);
    *(u16x4*)(Yb + (size_t)(tb + it) * 512) = o;
  }
}

// ---------------- GEMM: out[m][n] = sum_k A[m][k]*W[n][k] + bias + res ----------------
// BK=64: 8 K-phases of 32 MFMA each (halved barrier/drain overhead vs BK=32).
// LDS rows are 128 B -> bank-aliased, so the 16B chunk index is XOR-swizzled with
// (row&7) on BOTH sides (rule 21): linear LDS dest + pre-swizzled GLOBAL source
// chunk, and the same XOR on the ds_read chunk -> all 32 banks, 2-way (free).
__global__ __launch_bounds__(256) void gemm_bt(const u16* __restrict__ A, const u16* __restrict__ W,
                                               const float* __restrict__ bias, int nbias,
                                               const u16* __restrict__ res,
                                               u16* __restrict__ outb, float* __restrict__ outf,
                                               int ldo, int nstore) {
  union SM {
    struct { u16 A[2][8192]; u16 B[2][8192]; } s;  // 64 KB staging (double-buffered, BK=64)
    float o[64 * 132];                             // 33.8 KB epilogue half-tile
  };
  __shared__ __align__(16) SM sm;

  int tid = threadIdx.x;
  int m0 = blockIdx.x * 128;
  int n0 = blockIdx.y * 128;
  int lane = tid & 63, w = tid >> 6;
  int wm = (w & 1) * 64, wn = (w >> 1) * 64;
  int lr = lane & 15, kg = lane >> 4;

  f32x4 acc[4][4] = {};
  // staging: thread covers rows (tid>>3)+p*32 (p=0..3), 16B chunk (tid&7) of the
  // 64-col K-block; global source chunk is XOR-swizzled with row&7.
  int srow = tid >> 3;
  int srcc = (tid & 7) ^ (srow & 7);
  const u16* ga = A + (size_t)(m0 + srow) * 512 + srcc * 8;
  const u16* gb = W + (size_t)(n0 + srow) * 512 + srcc * 8;

  auto STAGE = [&](int buf, int kk) {
    const u16* ga0 = ga + kk * 64;
    const u16* gb0 = gb + kk * 64;
#pragma unroll
    for (int p = 0; p < 4; p++) {
      async16(ga0 + (size_t)p * 32 * 512, sm.s.A[buf] + tid * 8 + p * 2048);
      async16(gb0 + (size_t)p * 32 * 512, sm.s.B[buf] + tid * 8 + p * 2048);
    }
  };
  auto COMPUTE = [&](int buf) {
    bf16x8 af[2][4], bfr[2][4];
#pragma unroll
    for (int ks = 0; ks < 2; ks++) {
#pragma unroll
      for (int i = 0; i < 4; i++)
        af[ks][i] = *(const bf16x8*)(sm.s.A[buf] + (wm + i * 16 + lr) * 64 +
                                     (((ks * 4 + kg) ^ (lr & 7)) * 8));
#pragma unroll
      for (int j = 0; j < 4; j++)
        bfr[ks][j] = *(const bf16x8*)(sm.s.B[buf] + (wn + j * 16 + lr) * 64 +
                                      (((ks * 4 + kg) ^ (lr & 7)) * 8));
    }
#pragma unroll
    for (int ks = 0; ks < 2; ks++)
#pragma unroll
      for (int i = 0; i < 4; i++)
#pragma unroll
        for (int j = 0; j < 4; j++) acc[i][j] = MFMA16(af[ks][i], bfr[ks][j], acc[i][j]);
  };

  STAGE(0, 0);
  drain_vm();
  __syncthreads();
#pragma unroll
  for (int kk = 0; kk < 8; kk++) {
    if (kk < 7) STAGE((kk + 1) & 1, kk + 1);   // prefetch next K-block
    COMPUTE(kk & 1);
    drain_vm();                                 // next buf's LDS writes landed
    __syncthreads();
  }
  // loop's final barrier also fences last COMPUTE's ds_reads before epilogue aliasing

  // ---- epilogue: two row-halves through LDS, coalesced global I/O ----
#pragma unroll
  for (int half = 0; half < 2; half++) {
    if ((w & 1) == half) {         // waves owning rows [half*64, half*64+64)
#pragma unroll
      for (int i = 0; i < 4; i++)
#pragma unroll
        for (int j = 0; j < 4; j++) {
          int gn = n0 + wn + j * 16 + lr;
          float bv = (gn < nbias) ? bias[gn] : 0.f;
#pragma unroll
          for (int r = 0; r < 4; r++)
            sm.o[(i * 16 + kg * 4 + r) * 132 + wn + j * 16 + lr] = acc[i][j][r] + bv;
        }
    }
    __syncthreads();
    int rl = tid >> 4;             // 0..15
    int colv = (tid & 15) * 8;     // 0..120
#pragma unroll
    for (int p = 0; p < 4; p++) {
      int rrow = rl + p * 16;      // 0..63
      int m = m0 + half * 64 + rrow;
      const float* lp = sm.o + rrow * 132 + colv;
      f32x4 v0 = *(const f32x4*)lp;
      f32x4 v1 = *(const f32x4*)(lp + 4);
      if (res != nullptr) {
        u16x8 rv = *(const u16x8*)(res + (size_t)m * 512 + n0 + colv);
#pragma unroll
        for (int k = 0; k < 4; k++) { v0[k] += b2f(rv[k]); v1[k] += b2f(rv[4 + k]); }
      }
      if (outf != nullptr) {
        int gc = n0 + colv;
        if (gc + 4 <= nstore) *(f32x4*)(outf + (size_t)m * ldo + gc) = v0;
        if (gc + 8 <= nstore) *(f32x4*)(outf + (size_t)m * ldo + gc + 4) = v1;
      } else {
        u16x8 ov;
#pragma unroll
        for (int k = 0; k < 4; k++) { ov[k] = f2b(v0[k]); ov[4 + k] = f2b(v1[k]); }
        *(u16x8*)(outb + (size_t)m * ldo + n0 + colv) = ov;
      }
    }
    __syncthreads();
  }
}

// ---------------- QKV GEMM with head-separated scatter epilogue ----------------
// BK=32 3-buffer counted-vmcnt loop (6 blocks/CU grid; BK=64's 64 KB LDS would
// cut occupancy to 2 -> kept at 48 KB).
__global__ __launch_bounds__(256) void gemm_qkv(const u16* __restrict__ A, const u16* __restrict__ W,
                                                const float* __restrict__ bias, u16* __restrict__ out) {
  __shared__ __align__(16) u16 As[3][128 * 32];
  __shared__ __align__(16) u16 Bs[3][128 * 32];
  int tid = threadIdx.x;
  int m0 = blockIdx.x * 128;
  int n0 = blockIdx.y * 128;
  int lane = tid & 63, w = tid >> 6;
  int wm = (w & 1) * 64, wn = (w >> 1) * 64;
  int lr = lane & 15, kg = lane >> 4;

  f32x4 acc[4][4] = {};
  int row = tid >> 2, sub = tid & 3;
  const u16* ga = A + (size_t)(m0 + row) * 512 + sub * 8;
  const u16* gb = W + (size_t)(n0 + row) * 512 + sub * 8;

  auto STAGE = [&](int buf, int kk) {
    const u16* ga0 = ga + kk * 32;
    const u16* gb0 = gb + kk * 32;
    async16(ga0, As[buf] + tid * 8);
    async16(ga0 + 64 * 512, As[buf] + 2048 + tid * 8);
    async16(gb0, Bs[buf] + tid * 8);
    async16(gb0 + 64 * 512, Bs[buf] + 2048 + tid * 8);
  };
  auto COMPUTE = [&](int buf) {
    bf16x8 af[4], bfr[4];
#pragma unroll
    for (int i = 0; i < 4; i++) af[i] = *(const bf16x8*)(As[buf] + (wm + i * 16 + lr) * 32 + kg * 8);
#pragma unroll
    for (int j = 0; j < 4; j++) bfr[j] = *(const bf16x8*)(Bs[buf] + (wn + j * 16 + lr) * 32 + kg * 8);
#pragma unroll
    for (int i = 0; i < 4; i++)
#pragma unroll
      for (int j = 0; j < 4; j++) acc[i][j] = MFMA16(af[i], bfr[j], acc[i][j]);
  };

  STAGE(0, 0);
  STAGE(1, 1);
#pragma unroll
  for (int kk = 0; kk < 16; kk++) {
    if (kk < 15) wait_vm4();
    else         drain_vm();
    __builtin_amdgcn_sched_barrier(0);
    __syncthreads();
    if (kk + 2 < 16) STAGE((kk + 2) % 3, kk + 2);
    COMPUTE(kk % 3);
  }

#pragma unroll
  for (int i = 0; i < 4; i++) {
#pragma unroll
    for (int j = 0; j < 4; j++) {
      int n = n0 + wn + j * 16 + lr;
      if (n >= 1500) continue;
      int sel = n / 500;
      int rem = n - sel * 500;
      int head = rem / 50;
      int hd = rem - head * 50;
      float bv = bias[n];
#pragma unroll
      for (int r = 0; r < 4; r++) {
        int m = m0 + wm + i * 16 + kg * 4 + r;
        int bl = m >> 9, t = m & 511;
        size_t dst = ((size_t)(bl * 10 + head) * 3 + sel) * 32768 +
                     (sel < 2 ? (t * 64 + hd) : (hd * 512 + t));
        out[dst] = f2b(acc[i][j][r] + bv);
      }
    }
  }
}

// ---------------- fused attention (flash-style, online softmax) ----------------
// Grid (8,10,32) — the R6-measured-faster mapping (XCD swizzle reverted: it cut
// FETCH 174->31 MB but cost +7 µs; the re-fetch was L3-absorbed for free).
static constexpr int LP = 72;
__global__ __launch_bounds__(256) void attn(const u16* __restrict__ qkv, u16* __restrict__ att) {
  __shared__ __align__(16) u16 Qs[64 * LP];
  __shared__ __align__(16) u16 Ks[64 * LP];
  __shared__ __align__(16) u16 Vs[64 * LP];  // Vt[hd][t-within-tile]
  __shared__ __align__(16) u16 Ps[64 * LP];
  int tid = threadIdx.x;
  int qt = blockIdx.x, h = blockIdx.y, b = blockIdx.z;
  const u16* baseQ = qkv + ((size_t)(b * 10 + h) * 3 + 0) * 32768;
  const u16* baseK = baseQ + 32768;
  const u16* baseV = baseQ + 2 * 32768;

  int r0 = tid >> 3, cg = tid & 7;   // thread covers rows r0 and r0+32, col-group cg (8 u16)

  u32x4 kreg0, kreg1, vreg0, vreg1;
  auto LOADKV = [&](int kt) {
    const u16* pk = baseK + kt * 4096;
    const u16* pv = baseV + kt * 64;
    u32x4 z = {0, 0, 0, 0};
    kreg0 = (cg < 7) ? *(const u32x4*)(pk + r0 * 64 + cg * 8) : z;
    kreg1 = (cg < 7) ? *(const u32x4*)(pk + (r0 + 32) * 64 + cg * 8) : z;
    vreg0 = *(const u32x4*)(pv + (size_t)r0 * 512 + cg * 8);
    vreg1 = *(const u32x4*)(pv + (size_t)(r0 + 32) * 512 + cg * 8);
  };
  auto WRITEKV = [&]() {
    u32x4 k0 = kreg0, k1 = kreg1;
    if (cg == 6) { k0[1] = 0; k0[2] = 0; k0[3] = 0; k1[1] = 0; k1[2] = 0; k1[3] = 0; }
    *(u32x4*)(Ks + r0 * LP + cg * 8) = k0;
    *(u32x4*)(Ks + (r0 + 32) * LP + cg * 8) = k1;
    *(u32x4*)(Vs + r0 * LP + cg * 8) = vreg0;
    *(u32x4*)(Vs + (r0 + 32) * LP + cg * 8) = vreg1;
  };

  LOADKV(0);   // in flight during Q staging

  // stage Q tile with pad columns zeroed in the same pass
#pragma unroll
  for (int ii = 0; ii < 2; ii++) {
    int rr = r0 + ii * 32;
    u32x4 qv = {0, 0, 0, 0};
    if (cg < 7) qv = *(const u32x4*)(baseQ + qt * 4096 + rr * 64 + cg * 8);
    if (cg == 6) { qv[1] = 0; qv[2] = 0; qv[3] = 0; }
    *(u32x4*)(Qs + rr * LP + cg * 8) = qv;
  }
  __syncthreads();

  int lane = tid & 63, w = tid >> 6, lr = lane & 15, kg = lane >> 4;
  bf16x8 aq0 = *(const bf16x8*)(Qs + (w * 16 + lr) * LP + kg * 8);
  bf16x8 aq1 = *(const bf16x8*)(Qs + (w * 16 + lr) * LP + 32 + kg * 8);

  f32x4 O[4] = {};
  float mi[4], li[4];
#pragma unroll
  for (int i = 0; i < 4; i++) { mi[i] = -__builtin_inff(); li[i] = 0.f; }

  for (int kt = 0; kt < 8; kt++) {
    WRITEKV();                     // compiler inserts vmcnt wait on the staged regs
    if (kt < 7) LOADKV(kt + 1);    // issue next tile; flies during compute below
    __syncthreads();

    // S = Q K^T (each wave: its 16 q-rows x 64 k-cols)
    f32x4 sS[4];
#pragma unroll
    for (int j = 0; j < 4; j++) {
      bf16x8 bk0 = *(const bf16x8*)(Ks + (j * 16 + lr) * LP + kg * 8);
      bf16x8 bk1 = *(const bf16x8*)(Ks + (j * 16 + lr) * LP + 32 + kg * 8);
      f32x4 z = {0.f, 0.f, 0.f, 0.f};
      z = MFMA16(aq0, bk0, z);
      z = MFMA16(aq1, bk1, z);
      sS[j] = z;
    }

    // online softmax; C-layout: row = kg*4+rg, col = j*16+lr
#pragma unroll
    for (int rg = 0; rg < 4; rg++) {
      float mx = fmaxf(fmaxf(sS[0][rg], sS[1][rg]), fmaxf(sS[2][rg], sS[3][rg]));
      mx = fmaxf(mx, __shfl_xor(mx, 1));
      mx = fmaxf(mx, __shfl_xor(mx, 2));
      mx = fmaxf(mx, __shfl_xor(mx, 4));
      mx = fmaxf(mx, __shfl_xor(mx, 8));
      float mn = fmaxf(mi[rg], mx);
      float alpha = __expf(mi[rg] - mn);
      float rs = 0.f;
#pragma unroll
      for (int j = 0; j < 4; j++) {
        float p = __expf(sS[j][rg] - mn);
        sS[j][rg] = p;
        rs += p;
      }
      rs += __shfl_xor(rs, 1);
      rs += __shfl_xor(rs, 2);
      rs += __shfl_xor(rs, 4);
      rs += __shfl_xor(rs, 8);
      li[rg] = li[rg] * alpha + rs;
      mi[rg] = mn;
#pragma unroll
      for (int sb = 0; sb < 4; sb++) O[sb][rg] *= alpha;
#pragma unroll
      for (int j = 0; j < 4; j++)
        Ps[(w * 16 + kg * 4 + rg) * LP + j * 16 + lr] = f2b(sS[j][rg]);
    }

    // P (wave-private rows) -> A-frags; V^T rows as B operand
    bf16x8 ap0 = *(const bf16x8*)(Ps + (w * 16 + lr) * LP + kg * 8);
    bf16x8 ap1 = *(const bf16x8*)(Ps + (w * 16 + lr) * LP + 32 + kg * 8);
#pragma unroll
    for (int sb = 0; sb < 4; sb++) {
      bf16x8 bv0 = *(const bf16x8*)(Vs + (sb * 16 + lr) * LP + kg * 8);
      bf16x8 bv1 = *(const bf16x8*)(Vs + (sb * 16 + lr) * LP + 32 + kg * 8);
      O[sb] = MFMA16(ap0, bv0, O[sb]);
      O[sb] = MFMA16(ap1, bv1, O[sb]);
    }
    __syncthreads();               // Ks/Vs reads done before next WRITEKV
  }

#pragma unroll
  for (int rg = 0; rg < 4; rg++) {
    float inv = 1.f / li[rg];
    int t = qt * 64 + w * 16 + kg * 4 + rg;
    size_t rowbase = ((size_t)b * 512 + t) * 512;
#pragma unroll
    for (int sb = 0; sb < 4; sb++) {
      int hd = sb * 16 + lr;
      if (hd < 50)
        att[rowbase + h * 50 + hd] = f2b(O[sb][rg] * inv);
      else if (h == 9 && hd < 62)
        att[rowbase + 450 + hd] = 0;   // zero att pad cols 500..511
    }
  }
}

// ---------------- workspace layout (~114 MiB of the ~268 MiB ws) ----------------
static constexpr size_t MB = 1024 * 1024;
static constexpr size_t OFF_S0  = 0;                      // [0,16M)    x0 / out3 (bf16)
static constexpr size_t OFF_S1  = 16 * MB;                // [16M,32M)  ping-pong, then ATT
static constexpr size_t OFF_R   = 32 * MB;                // [32M,48M)  DW scratch -> OUT4
static constexpr size_t OFF_QKV = 48 * MB;                // [48M,108M) full head-separated QKV (60 MB)
static constexpr size_t OFF_PE  = 108 * MB;               // f32[512*512] (1 MB)
static constexpr size_t OFF_PW  = 109 * MB;
static constexpr size_t SZ_W = (size_t)512 * 512 * 2;
static constexpr size_t OFF_OW = OFF_PW + 4 * SZ_W;
static constexpr size_t OFF_FW = OFF_OW + SZ_W;
static constexpr size_t OFF_INW = OFF_FW + SZ_W;
static constexpr size_t OFF_INB = OFF_INW + (size_t)1536 * 512 * 2;   // f32[1536]

extern "C" void kernel_launch(void* const* d_in, const int* in_sizes, int n_in,
                              void* d_out, int out_size, void* d_ws, size_t ws_size,
                              hipStream_t stream) {
  const int* ori = (const int*)d_in[0];
  const float* x = (const float*)d_in[1];
  const float* dwv[4] = {(const float*)d_in[3], (const float*)d_in[7], (const float*)d_in[11], (const float*)d_in[15]};
  const float* dbv[4] = {(const float*)d_in[4], (const float*)d_in[8], (const float*)d_in[12], (const float*)d_in[16]};
  const float* pwv[4] = {(const float*)d_in[5], (const float*)d_in[9], (const float*)d_in[13], (const float*)d_in[17]};
  const float* pbv[4] = {(const float*)d_in[6], (const float*)d_in[10], (const float*)d_in[14], (const float*)d_in[18]};
  const float* in_w = (const float*)d_in[19];
  const float* in_b = (const float*)d_in[20];
  const float* out_w = (const float*)d_in[21];
  const float* out_b = (const float*)d_in[22];
  const float* ffc_w = (const float*)d_in[23];
  const float* ffc_b = (const float*)d_in[24];

  char* ws = (char*)d_ws;
  u16* S0  = (u16*)(ws + OFF_S0);
  u16* S1  = (u16*)(ws + OFF_S1);
  u16* R   = (u16*)(ws + OFF_R);
  u16* QKV = (u16*)(ws + OFF_QKV);
  float* PE = (float*)(ws + OFF_PE);
  u16* PW  = (u16*)(ws + OFF_PW);
  u16* OW  = (u16*)(ws + OFF_OW);
  u16* FW  = (u16*)(ws + OFF_FW);
  u16* INW = (u16*)(ws + OFF_INW);
  float* INB = (float*)(ws + OFF_INB);

  // all weight packing + PE table in one launch
  packall<<<5126, 256, 0, stream>>>(pwv[0], pwv[1], pwv[2], pwv[3], out_w, ffc_w, in_w, in_b,
                                    PW, OW, FW, INW, INB, PE);

  // x0 = pos_emb + x (table lookup)
  posemb<<<M, 256, 0, stream>>>(ori, x, PE, S0);

  // 4x sepconv + residual (DW scratch in R)
  u16* cur = S0;
  u16* nxt = S1;
  for (int i = 0; i < 4; i++) {
    dwconv<<<dim3(64, 32), 256, 0, stream>>>(cur, dwv[i], dbv[i], R);
    gemm_bt<<<dim3(128, 4), 256, 0, stream>>>(R, PW + (size_t)i * 512 * 512, pbv[i], 500,
                                              cur, nxt, nullptr, 512, 512);
    u16* t2 = cur; cur = nxt; nxt = t2;
  }
  // cur == S0 holds out3; S1 free

  // qkv projection (full batch) + attention (full batch); ATT = S1
  gemm_qkv<<<dim3(128, 12), 256, 0, stream>>>(cur, INW, INB, QKV);
  attn<<<dim3(8, 10, 32), 256, 0, stream>>>(QKV, S1);

  // out_proj + residual(out3=S0) -> OUT4 in R
  gemm_bt<<<dim3(128, 4), 256, 0, stream>>>(S1, OW, out_b, 500, cur, R, nullptr, 512, 512);

  // ffc + residual(OUT4) -> d_out f32 [M][500]
  gemm_bt<<<dim3(128, 4), 256, 0, stream>>>(R, FW, ffc_b, 500, R, nullptr, (float*)d_out, 500, 500);
}

// Round 11
// 458.311 us; speedup vs baseline: 1.0430x; 1.0158x over previous
//
#include <hip/hip_runtime.h>
#include <cstdint>
#include <cstddef>

typedef unsigned short u16;
typedef __bf16 bf16x8 __attribute__((ext_vector_type(8)));
typedef float f32x4 __attribute__((ext_vector_type(4)));
typedef unsigned int u32;
typedef u32 u32x4 __attribute__((ext_vector_type(4)));
typedef u16 u16x8 __attribute__((ext_vector_type(8)));
typedef u16 u16x4 __attribute__((ext_vector_type(4)));

#define MFMA16(a, b, c) __builtin_amdgcn_mfma_f32_16x16x32_bf16((a), (b), (c), 0, 0, 0)

static constexpr int B = 32, T = 512, D = 500, H = 10, HD = 50;
static constexpr int M = B * T;          // 16384 tokens

__device__ __forceinline__ float b2f(u16 u) { return (float)__builtin_bit_cast(__bf16, u); }
__device__ __forceinline__ u16 f2b(float f) { return __builtin_bit_cast(u16, (__bf16)f); }

__device__ __forceinline__ void async16(const void* g, void* s) {
  __builtin_amdgcn_global_load_lds((const __attribute__((address_space(1))) void*)g,
                                   (__attribute__((address_space(3))) void*)s, 16, 0, 0);
}

__device__ __forceinline__ void wait_vm4() {
  asm volatile("s_waitcnt vmcnt(4)" ::: "memory");
}
__device__ __forceinline__ void drain_vm() {
  asm volatile("s_waitcnt vmcnt(0)" ::: "memory");
}

// ---------------- all weight packing + PE table in ONE kernel ----------------
__global__ __launch_bounds__(256) void packall(
    const float* __restrict__ pw0, const float* __restrict__ pw1,
    const float* __restrict__ pw2, const float* __restrict__ pw3,
    const float* __restrict__ ow, const float* __restrict__ fw,
    const float* __restrict__ inw, const float* __restrict__ inb,
    u16* __restrict__ PW, u16* __restrict__ OW, u16* __restrict__ FW,
    u16* __restrict__ INW, float* __restrict__ INB, float* __restrict__ PE) {
  int bx = blockIdx.x;
  if (bx < 3072) {
    int which = bx >> 9, o = bx & 511;
    const float* src = which == 0 ? pw0 : which == 1 ? pw1 : which == 2 ? pw2
                     : which == 3 ? pw3 : which == 4 ? ow : fw;
    u16* dst = which < 4 ? PW + (size_t)which * 512 * 512 : (which == 4 ? OW : FW);
    for (int c = threadIdx.x; c < 512; c += 256)
      dst[o * 512 + c] = (o < 500 && c < 500) ? f2b(src[o * 500 + c]) : (u16)0;
    return;
  }
  bx -= 3072;
  if (bx < 1536) {
    int e = bx;
    for (int c = threadIdx.x; c < 512; c += 256) {
      u16 v = 0;
      if (e < 1500 && c < 500) {
        float f = inw[e * 500 + c];
        if (e < 500) f *= 0.14142135623730951f;
        v = f2b(f);
      }
      INW[e * 512 + c] = v;
    }
    return;
  }
  bx -= 1536;
  if (bx < 512) {
    int t = bx;
    float fp = (float)(t + 1);
    for (int d = threadIdx.x; d < 512; d += 256) {
      float pe = 0.f;
      if (d < 500) {
        int i = (d < 250) ? d : d - 250;
        float ang = fp * expf((float)i * -0.036989318762956f); // -ln(10000)/249
        pe = (d < 250) ? sinf(ang) : cosf(ang);
      }
      PE[t * 512 + d] = pe;
    }
    return;
  }
  bx -= 512;
  int e = bx * 256 + threadIdx.x;
  if (e < 1536) {
    float f = 0.f;
    if (e < 1500) {
      f = inb[e];
      if (e < 500) f *= 0.14142135623730951f;
    }
    INB[e] = f;
  }
}

// ---------------- positional embedding + add (table lookup, no trig) ----------------
__global__ __launch_bounds__(256) void posemb(const int* __restrict__ ori, const float* __restrict__ x,
                                              const float* __restrict__ PE, u16* __restrict__ out) {
  int m = blockIdx.x;
  int t = m & 511;
  bool np = (ori[m] != 0);
  for (int d = threadIdx.x; d < 512; d += 256) {
    float v = 0.f;
    if (d < 500) {
      float pe = np ? PE[t * 512 + d] : 0.f;
      v = pe + x[(size_t)m * 500 + d];
    }
    out[(size_t)m * 512 + d] = f2b(v);
  }
}

// ---------------- depthwise conv (k=7, pad=3) along T ----------------
__global__ __launch_bounds__(256) void dwconv(const u16* __restrict__ X, const float* __restrict__ dw,
                                              const float* __restrict__ db, u16* __restrict__ Y) {
  int b = blockIdx.y;
  int t0 = blockIdx.x * 8;
  int c0 = (threadIdx.x & 127) * 4;  // channel base (0..508)
  int ts = threadIdx.x >> 7;         // 0..1
  int tb = t0 + ts * 4;              // first output t (consecutive 4)

  float wv[7][4];
  float bias[4];
#pragma unroll
  for (int j = 0; j < 4; j++) {
    int c = c0 + j;
    bool ok = (c < 500);
    bias[j] = ok ? db[c] : 0.f;
#pragma unroll
    for (int k = 0; k < 7; k++) wv[k][j] = ok ? dw[c * 7 + k] : 0.f;
  }

  const u16* Xb = X + (size_t)b * 512 * 512 + c0;
  u16* Yb = Y + (size_t)b * 512 * 512 + c0;

  u16x4 xr[10];
#pragma unroll
  for (int k = 0; k < 10; k++) {
    int tt = tb - 3 + k;
    u16x4 z = {0, 0, 0, 0};
    xr[k] = (tt >= 0 && tt < 512) ? *(const u16x4*)(Xb + (size_t)tt * 512) : z;
  }

#pragma unroll
  for (int it = 0; it < 4; it++) {
    float acc[4] = {bias[0], bias[1], bias[2], bias[3]};
#pragma unroll
    for (int k = 0; k < 7; k++)
#pragma unroll
      for (int j = 0; j < 4; j++)
        acc[j] += wv[k][j] * b2f(xr[it + k][j]);
    u16x4 o;
#pragma unroll
    for (int j = 0; j < 4; j++) o[j] = f2b(acc[j]);
    *(u16x4*)(Yb + (size_t)(tb + it) * 512) = o;
  }
}

// ---------------- GEMM: out[m][n] = sum_k A[m][k]*W[n][k] + bias + res ----------------
// BK=64, XOR-swizzled staging (rule 21: pre-swizzled global source + same XOR on read).
__global__ __launch_bounds__(256) void gemm_bt(const u16* __restrict__ A, const u16* __restrict__ W,
                                               const float* __restrict__ bias, int nbias,
                                               const u16* __restrict__ res,
                                               u16* __restrict__ outb, float* __restrict__ outf,
                                               int ldo, int nstore) {
  union SM {
    struct { u16 A[2][8192]; u16 B[2][8192]; } s;  // 64 KB staging (double-buffered, BK=64)
    float o[64 * 132];                             // 33.8 KB epilogue half-tile
  };
  __shared__ __align__(16) SM sm;

  int tid = threadIdx.x;
  int m0 = blockIdx.x * 128;
  int n0 = blockIdx.y * 128;
  int lane = tid & 63, w = tid >> 6;
  int wm = (w & 1) * 64, wn = (w >> 1) * 64;
  int lr = lane & 15, kg = lane >> 4;

  f32x4 acc[4][4] = {};
  int srow = tid >> 3;
  int srcc = (tid & 7) ^ (srow & 7);
  const u16* ga = A + (size_t)(m0 + srow) * 512 + srcc * 8;
  const u16* gb = W + (size_t)(n0 + srow) * 512 + srcc * 8;

  auto STAGE = [&](int buf, int kk) {
    const u16* ga0 = ga + kk * 64;
    const u16* gb0 = gb + kk * 64;
#pragma unroll
    for (int p = 0; p < 4; p++) {
      async16(ga0 + (size_t)p * 32 * 512, sm.s.A[buf] + tid * 8 + p * 2048);
      async16(gb0 + (size_t)p * 32 * 512, sm.s.B[buf] + tid * 8 + p * 2048);
    }
  };
  auto COMPUTE = [&](int buf) {
    bf16x8 af[2][4], bfr[2][4];
#pragma unroll
    for (int ks = 0; ks < 2; ks++) {
#pragma unroll
      for (int i = 0; i < 4; i++)
        af[ks][i] = *(const bf16x8*)(sm.s.A[buf] + (wm + i * 16 + lr) * 64 +
                                     (((ks * 4 + kg) ^ (lr & 7)) * 8));
#pragma unroll
      for (int j = 0; j < 4; j++)
        bfr[ks][j] = *(const bf16x8*)(sm.s.B[buf] + (wn + j * 16 + lr) * 64 +
                                      (((ks * 4 + kg) ^ (lr & 7)) * 8));
    }
#pragma unroll
    for (int ks = 0; ks < 2; ks++)
#pragma unroll
      for (int i = 0; i < 4; i++)
#pragma unroll
        for (int j = 0; j < 4; j++) acc[i][j] = MFMA16(af[ks][i], bfr[ks][j], acc[i][j]);
  };

  STAGE(0, 0);
  drain_vm();
  __syncthreads();
#pragma unroll
  for (int kk = 0; kk < 8; kk++) {
    if (kk < 7) STAGE((kk + 1) & 1, kk + 1);   // prefetch next K-block
    COMPUTE(kk & 1);
    drain_vm();                                 // next buf's LDS writes landed
    __syncthreads();
  }

  // ---- epilogue: two row-halves through LDS, coalesced global I/O ----
#pragma unroll
  for (int half = 0; half < 2; half++) {
    if ((w & 1) == half) {
#pragma unroll
      for (int i = 0; i < 4; i++)
#pragma unroll
        for (int j = 0; j < 4; j++) {
          int gn = n0 + wn + j * 16 + lr;
          float bv = (gn < nbias) ? bias[gn] : 0.f;
#pragma unroll
          for (int r = 0; r < 4; r++)
            sm.o[(i * 16 + kg * 4 + r) * 132 + wn + j * 16 + lr] = acc[i][j][r] + bv;
        }
    }
    __syncthreads();
    int rl = tid >> 4;
    int colv = (tid & 15) * 8;
#pragma unroll
    for (int p = 0; p < 4; p++) {
      int rrow = rl + p * 16;
      int m = m0 + half * 64 + rrow;
      const float* lp = sm.o + rrow * 132 + colv;
      f32x4 v0 = *(const f32x4*)lp;
      f32x4 v1 = *(const f32x4*)(lp + 4);
      if (res != nullptr) {
        u16x8 rv = *(const u16x8*)(res + (size_t)m * 512 + n0 + colv);
#pragma unroll
        for (int k = 0; k < 4; k++) { v0[k] += b2f(rv[k]); v1[k] += b2f(rv[4 + k]); }
      }
      if (outf != nullptr) {
        int gc = n0 + colv;
        if (gc + 4 <= nstore) *(f32x4*)(outf + (size_t)m * ldo + gc) = v0;
        if (gc + 8 <= nstore) *(f32x4*)(outf + (size_t)m * ldo + gc + 4) = v1;
      } else {
        u16x8 ov;
#pragma unroll
        for (int k = 0; k < 4; k++) { ov[k] = f2b(v0[k]); ov[4 + k] = f2b(v1[k]); }
        *(u16x8*)(outb + (size_t)m * ldo + n0 + colv) = ov;
      }
    }
    __syncthreads();
  }
}

// ---------------- QKV GEMM with head-separated scatter epilogue ----------------
__global__ __launch_bounds__(256) void gemm_qkv(const u16* __restrict__ A, const u16* __restrict__ W,
                                                const float* __restrict__ bias, u16* __restrict__ out) {
  __shared__ __align__(16) u16 As[3][128 * 32];
  __shared__ __align__(16) u16 Bs[3][128 * 32];
  int tid = threadIdx.x;
  int m0 = blockIdx.x * 128;
  int n0 = blockIdx.y * 128;
  int lane = tid & 63, w = tid >> 6;
  int wm = (w & 1) * 64, wn = (w >> 1) * 64;
  int lr = lane & 15, kg = lane >> 4;

  f32x4 acc[4][4] = {};
  int row = tid >> 2, sub = tid & 3;
  const u16* ga = A + (size_t)(m0 + row) * 512 + sub * 8;
  const u16* gb = W + (size_t)(n0 + row) * 512 + sub * 8;

  auto STAGE = [&](int buf, int kk) {
    const u16* ga0 = ga + kk * 32;
    const u16* gb0 = gb + kk * 32;
    async16(ga0, As[buf] + tid * 8);
    async16(ga0 + 64 * 512, As[buf] + 2048 + tid * 8);
    async16(gb0, Bs[buf] + tid * 8);
    async16(gb0 + 64 * 512, Bs[buf] + 2048 + tid * 8);
  };
  auto COMPUTE = [&](int buf) {
    bf16x8 af[4], bfr[4];
#pragma unroll
    for (int i = 0; i < 4; i++) af[i] = *(const bf16x8*)(As[buf] + (wm + i * 16 + lr) * 32 + kg * 8);
#pragma unroll
    for (int j = 0; j < 4; j++) bfr[j] = *(const bf16x8*)(Bs[buf] + (wn + j * 16 + lr) * 32 + kg * 8);
#pragma unroll
    for (int i = 0; i < 4; i++)
#pragma unroll
      for (int j = 0; j < 4; j++) acc[i][j] = MFMA16(af[i], bfr[j], acc[i][j]);
  };

  STAGE(0, 0);
  STAGE(1, 1);
#pragma unroll
  for (int kk = 0; kk < 16; kk++) {
    if (kk < 15) wait_vm4();
    else         drain_vm();
    __builtin_amdgcn_sched_barrier(0);
    __syncthreads();
    if (kk + 2 < 16) STAGE((kk + 2) % 3, kk + 2);
    COMPUTE(kk % 3);
  }

#pragma unroll
  for (int i = 0; i < 4; i++) {
#pragma unroll
    for (int j = 0; j < 4; j++) {
      int n = n0 + wn + j * 16 + lr;
      if (n >= 1500) continue;
      int sel = n / 500;
      int rem = n - sel * 500;
      int head = rem / 50;
      int hd = rem - head * 50;
      float bv = bias[n];
#pragma unroll
      for (int r = 0; r < 4; r++) {
        int m = m0 + wm + i * 16 + kg * 4 + r;
        int bl = m >> 9, t = m & 511;
        size_t dst = ((size_t)(bl * 10 + head) * 3 + sel) * 32768 +
                     (sel < 2 ? (t * 64 + hd) : (hd * 512 + t));
        out[dst] = f2b(acc[i][j][r] + bv);
      }
    }
  }
}

// ---------------- fused attention (flash-style, online softmax) ----------------
// SWAPPED QK^T (mfma(K,Q)): C col=lane&15 = q, row = k -> each lane holds 16
// S-values of ONE q-row. Row max/sum become in-register VALU trees + 2 shfls
// (vs 32 LDS-pipe shfls/kt before). P written packed (u16x4, rg-consecutive k).
// Per-q alpha / final 1/li broadcast to the O-layout (q=kg*4+rg) via a tiny
// per-wave LDS array (within-wave, lgkmcnt-ordered).
static constexpr int LP = 72;
__global__ __launch_bounds__(256) void attn(const u16* __restrict__ qkv, u16* __restrict__ att) {
  __shared__ __align__(16) u16 Qs[64 * LP];
  __shared__ __align__(16) u16 Ks[64 * LP];
  __shared__ __align__(16) u16 Vs[64 * LP];  // Vt[hd][t-within-tile]
  __shared__ __align__(16) u16 Ps[64 * LP];
  __shared__ __align__(16) float Al[4][16];  // per-wave alpha / li broadcast
  int tid = threadIdx.x;
  int qt = blockIdx.x, h = blockIdx.y, b = blockIdx.z;
  const u16* baseQ = qkv + ((size_t)(b * 10 + h) * 3 + 0) * 32768;
  const u16* baseK = baseQ + 32768;
  const u16* baseV = baseQ + 2 * 32768;

  int r0 = tid >> 3, cg = tid & 7;

  u32x4 kreg0, kreg1, vreg0, vreg1;
  auto LOADKV = [&](int kt) {
    const u16* pk = baseK + kt * 4096;
    const u16* pv = baseV + kt * 64;
    u32x4 z = {0, 0, 0, 0};
    kreg0 = (cg < 7) ? *(const u32x4*)(pk + r0 * 64 + cg * 8) : z;
    kreg1 = (cg < 7) ? *(const u32x4*)(pk + (r0 + 32) * 64 + cg * 8) : z;
    vreg0 = *(const u32x4*)(pv + (size_t)r0 * 512 + cg * 8);
    vreg1 = *(const u32x4*)(pv + (size_t)(r0 + 32) * 512 + cg * 8);
  };
  auto WRITEKV = [&]() {
    u32x4 k0 = kreg0, k1 = kreg1;
    if (cg == 6) { k0[1] = 0; k0[2] = 0; k0[3] = 0; k1[1] = 0; k1[2] = 0; k1[3] = 0; }
    *(u32x4*)(Ks + r0 * LP + cg * 8) = k0;
    *(u32x4*)(Ks + (r0 + 32) * LP + cg * 8) = k1;
    *(u32x4*)(Vs + r0 * LP + cg * 8) = vreg0;
    *(u32x4*)(Vs + (r0 + 32) * LP + cg * 8) = vreg1;
  };

  LOADKV(0);   // in flight during Q staging

#pragma unroll
  for (int ii = 0; ii < 2; ii++) {
    int rr = r0 + ii * 32;
    u32x4 qv = {0, 0, 0, 0};
    if (cg < 7) qv = *(const u32x4*)(baseQ + qt * 4096 + rr * 64 + cg * 8);
    if (cg == 6) { qv[1] = 0; qv[2] = 0; qv[3] = 0; }
    *(u32x4*)(Qs + rr * LP + cg * 8) = qv;
  }
  __syncthreads();

  int lane = tid & 63, w = tid >> 6, lr = lane & 15, kg = lane >> 4;
  // Q as B-operand (lane&15 = q-col): same addresses as before
  bf16x8 bq0 = *(const bf16x8*)(Qs + (w * 16 + lr) * LP + kg * 8);
  bf16x8 bq1 = *(const bf16x8*)(Qs + (w * 16 + lr) * LP + 32 + kg * 8);

  f32x4 O[4] = {};
  float mi = -__builtin_inff();   // running max for q = w*16+lr (dup across kg)
  float li = 0.f;                 // running sum for q = w*16+lr

  for (int kt = 0; kt < 8; kt++) {
    WRITEKV();
    if (kt < 7) LOADKV(kt + 1);
    __syncthreads();

    // S^T = K Q^T: lane holds S[q=w*16+lr][k=j*16+kg*4+rg]
    f32x4 s[4];
#pragma unroll
    for (int j = 0; j < 4; j++) {
      bf16x8 ak0 = *(const bf16x8*)(Ks + (j * 16 + lr) * LP + kg * 8);
      bf16x8 ak1 = *(const bf16x8*)(Ks + (j * 16 + lr) * LP + 32 + kg * 8);
      f32x4 z = {0.f, 0.f, 0.f, 0.f};
      z = MFMA16(ak0, bq0, z);
      z = MFMA16(ak1, bq1, z);
      s[j] = z;
    }

    // in-register row reduction (16 values) + 2 cross-group shfls
    f32x4 m4 = s[0];
#pragma unroll
    for (int j = 1; j < 4; j++)
#pragma unroll
      for (int rg = 0; rg < 4; rg++) m4[rg] = fmaxf(m4[rg], s[j][rg]);
    float mx = fmaxf(fmaxf(m4[0], m4[1]), fmaxf(m4[2], m4[3]));
    mx = fmaxf(mx, __shfl_xor(mx, 16));
    mx = fmaxf(mx, __shfl_xor(mx, 32));

    float mn = fmaxf(mi, mx);
    float alpha = __expf(mi - mn);
#pragma unroll
    for (int j = 0; j < 4; j++)
#pragma unroll
      for (int rg = 0; rg < 4; rg++) s[j][rg] = __expf(s[j][rg] - mn);
    f32x4 s4 = s[0];
#pragma unroll
    for (int j = 1; j < 4; j++)
#pragma unroll
      for (int rg = 0; rg < 4; rg++) s4[rg] += s[j][rg];
    float rs = (s4[0] + s4[1]) + (s4[2] + s4[3]);
    rs += __shfl_xor(rs, 16);
    rs += __shfl_xor(rs, 32);
    li = li * alpha + rs;
    mi = mn;

    // packed P write: rg are consecutive k -> u16x4 per j
#pragma unroll
    for (int j = 0; j < 4; j++) {
      u16x4 pv4 = {f2b(s[j][0]), f2b(s[j][1]), f2b(s[j][2]), f2b(s[j][3])};
      *(u16x4*)(Ps + (w * 16 + lr) * LP + j * 16 + kg * 4) = pv4;
    }

    // broadcast alpha (per q=lr) to O-layout rows (q=kg*4+rg)
    if (kg == 0) Al[w][lr] = alpha;
    f32x4 av = *(const f32x4*)&Al[w][kg * 4];
#pragma unroll
    for (int sb = 0; sb < 4; sb++)
#pragma unroll
      for (int rg = 0; rg < 4; rg++) O[sb][rg] *= av[rg];

    // PV (forward): A = P rows, B = V^T rows
    bf16x8 ap0 = *(const bf16x8*)(Ps + (w * 16 + lr) * LP + kg * 8);
    bf16x8 ap1 = *(const bf16x8*)(Ps + (w * 16 + lr) * LP + 32 + kg * 8);
#pragma unroll
    for (int sb = 0; sb < 4; sb++) {
      bf16x8 bv0 = *(const bf16x8*)(Vs + (sb * 16 + lr) * LP + kg * 8);
      bf16x8 bv1 = *(const bf16x8*)(Vs + (sb * 16 + lr) * LP + 32 + kg * 8);
      O[sb] = MFMA16(ap0, bv0, O[sb]);
      O[sb] = MFMA16(ap1, bv1, O[sb]);
    }
    __syncthreads();               // Ks/Vs reads done before next WRITEKV
  }

  // broadcast final li to O-layout rows
  if (kg == 0) Al[w][lr] = li;
  f32x4 lv = *(const f32x4*)&Al[w][kg * 4];

#pragma unroll
  for (int rg = 0; rg < 4; rg++) {
    float inv = 1.f / lv[rg];
    int t = qt * 64 + w * 16 + kg * 4 + rg;
    size_t rowbase = ((size_t)b * 512 + t) * 512;
#pragma unroll
    for (int sb = 0; sb < 4; sb++) {
      int hd = sb * 16 + lr;
      if (hd < 50)
        att[rowbase + h * 50 + hd] = f2b(O[sb][rg] * inv);
      else if (h == 9 && hd < 62)
        att[rowbase + 450 + hd] = 0;   // zero att pad cols 500..511
    }
  }
}

// ---------------- workspace layout (~114 MiB of the ~268 MiB ws) ----------------
static constexpr size_t MB = 1024 * 1024;
static constexpr size_t OFF_S0  = 0;                      // [0,16M)    x0 / out3 (bf16)
static constexpr size_t OFF_S1  = 16 * MB;                // [16M,32M)  ping-pong, then ATT
static constexpr size_t OFF_R   = 32 * MB;                // [32M,48M)  DW scratch -> OUT4
static constexpr size_t OFF_QKV = 48 * MB;                // [48M,108M) full head-separated QKV (60 MB)
static constexpr size_t OFF_PE  = 108 * MB;               // f32[512*512] (1 MB)
static constexpr size_t OFF_PW  = 109 * MB;
static constexpr size_t SZ_W = (size_t)512 * 512 * 2;
static constexpr size_t OFF_OW = OFF_PW + 4 * SZ_W;
static constexpr size_t OFF_FW = OFF_OW + SZ_W;
static constexpr size_t OFF_INW = OFF_FW + SZ_W;
static constexpr size_t OFF_INB = OFF_INW + (size_t)1536 * 512 * 2;   // f32[1536]

extern "C" void kernel_launch(void* const* d_in, const int* in_sizes, int n_in,
                              void* d_out, int out_size, void* d_ws, size_t ws_size,
                              hipStream_t stream) {
  const int* ori = (const int*)d_in[0];
  const float* x = (const float*)d_in[1];
  const float* dwv[4] = {(const float*)d_in[3], (const float*)d_in[7], (const float*)d_in[11], (const float*)d_in[15]};
  const float* dbv[4] = {(const float*)d_in[4], (const float*)d_in[8], (const float*)d_in[12], (const float*)d_in[16]};
  const float* pwv[4] = {(const float*)d_in[5], (const float*)d_in[9], (const float*)d_in[13], (const float*)d_in[17]};
  const float* pbv[4] = {(const float*)d_in[6], (const float*)d_in[10], (const float*)d_in[14], (const float*)d_in[18]};
  const float* in_w = (const float*)d_in[19];
  const float* in_b = (const float*)d_in[20];
  const float* out_w = (const float*)d_in[21];
  const float* out_b = (const float*)d_in[22];
  const float* ffc_w = (const float*)d_in[23];
  const float* ffc_b = (const float*)d_in[24];

  char* ws = (char*)d_ws;
  u16* S0  = (u16*)(ws + OFF_S0);
  u16* S1  = (u16*)(ws + OFF_S1);
  u16* R   = (u16*)(ws + OFF_R);
  u16* QKV = (u16*)(ws + OFF_QKV);
  float* PE = (float*)(ws + OFF_PE);
  u16* PW  = (u16*)(ws + OFF_PW);
  u16* OW  = (u16*)(ws + OFF_OW);
  u16* FW  = (u16*)(ws + OFF_FW);
  u16* INW = (u16*)(ws + OFF_INW);
  float* INB = (float*)(ws + OFF_INB);

  // all weight packing + PE table in one launch
  packall<<<5126, 256, 0, stream>>>(pwv[0], pwv[1], pwv[2], pwv[3], out_w, ffc_w, in_w, in_b,
                                    PW, OW, FW, INW, INB, PE);

  // x0 = pos_emb + x (table lookup)
  posemb<<<M, 256, 0, stream>>>(ori, x, PE, S0);

  // 4x sepconv + residual (DW scratch in R)
  u16* cur = S0;
  u16* nxt = S1;
  for (int i = 0; i < 4; i++) {
    dwconv<<<dim3(64, 32), 256, 0, stream>>>(cur, dwv[i], dbv[i], R);
    gemm_bt<<<dim3(128, 4), 256, 0, stream>>>(R, PW + (size_t)i * 512 * 512, pbv[i], 500,
                                              cur, nxt, nullptr, 512, 512);
    u16* t2 = cur; cur = nxt; nxt = t2;
  }
  // cur == S0 holds out3; S1 free

  // qkv projection (full batch) + attention (full batch); ATT = S1
  gemm_qkv<<<dim3(128, 12), 256, 0, stream>>>(cur, INW, INB, QKV);
  attn<<<dim3(8, 10, 32), 256, 0, stream>>>(QKV, S1);

  // out_proj + residual(out3=S0) -> OUT4 in R
  gemm_bt<<<dim3(128, 4), 256, 0, stream>>>(S1, OW, out_b, 500, cur, R, nullptr, 512, 512);

  // ffc + residual(OUT4) -> d_out f32 [M][500]
  gemm_bt<<<dim3(128, 4), 256, 0, stream>>>(R, FW, ffc_b, 500, R, nullptr, (float*)d_out, 500, 500);
}

// Round 13
// 445.396 us; speedup vs baseline: 1.0733x; 1.0290x over previous
//
#include <hip/hip_runtime.h>
#include <cstdint>
#include <cstddef>

typedef unsigned short u16;
typedef __bf16 bf16x8 __attribute__((ext_vector_type(8)));
typedef float f32x4 __attribute__((ext_vector_type(4)));
typedef unsigned int u32;
typedef u32 u32x4 __attribute__((ext_vector_type(4)));
typedef u16 u16x8 __attribute__((ext_vector_type(8)));
typedef u16 u16x4 __attribute__((ext_vector_type(4)));

#define MFMA16(a, b, c) __builtin_amdgcn_mfma_f32_16x16x32_bf16((a), (b), (c), 0, 0, 0)

static constexpr int B = 32, T = 512, D = 500, H = 10, HD = 50;
static constexpr int M = B * T;          // 16384 tokens

__device__ __forceinline__ float b2f(u16 u) { return (float)__builtin_bit_cast(__bf16, u); }
__device__ __forceinline__ u16 f2b(float f) { return __builtin_bit_cast(u16, (__bf16)f); }

__device__ __forceinline__ void async16(const void* g, void* s) {
  __builtin_amdgcn_global_load_lds((const __attribute__((address_space(1))) void*)g,
                                   (__attribute__((address_space(3))) void*)s, 16, 0, 0);
}

__device__ __forceinline__ void wait_vm4() {
  asm volatile("s_waitcnt vmcnt(4)" ::: "memory");
}
__device__ __forceinline__ void drain_vm() {
  asm volatile("s_waitcnt vmcnt(0)" ::: "memory");
}

// ---------------- all weight packing + PE table in ONE kernel ----------------
__global__ __launch_bounds__(256) void packall(
    const float* __restrict__ pw0, const float* __restrict__ pw1,
    const float* __restrict__ pw2, const float* __restrict__ pw3,
    const float* __restrict__ ow, const float* __restrict__ fw,
    const float* __restrict__ inw, const float* __restrict__ inb,
    u16* __restrict__ PW, u16* __restrict__ OW, u16* __restrict__ FW,
    u16* __restrict__ INW, float* __restrict__ INB, float* __restrict__ PE) {
  int bx = blockIdx.x;
  if (bx < 3072) {
    int which = bx >> 9, o = bx & 511;
    const float* src = which == 0 ? pw0 : which == 1 ? pw1 : which == 2 ? pw2
                     : which == 3 ? pw3 : which == 4 ? ow : fw;
    u16* dst = which < 4 ? PW + (size_t)which * 512 * 512 : (which == 4 ? OW : FW);
    for (int c = threadIdx.x; c < 512; c += 256)
      dst[o * 512 + c] = (o < 500 && c < 500) ? f2b(src[o * 500 + c]) : (u16)0;
    return;
  }
  bx -= 3072;
  if (bx < 1536) {
    int e = bx;
    for (int c = threadIdx.x; c < 512; c += 256) {
      u16 v = 0;
      if (e < 1500 && c < 500) {
        float f = inw[e * 500 + c];
        if (e < 500) f *= 0.14142135623730951f;
        v = f2b(f);
      }
      INW[e * 512 + c] = v;
    }
    return;
  }
  bx -= 1536;
  if (bx < 512) {
    int t = bx;
    float fp = (float)(t + 1);
    for (int d = threadIdx.x; d < 512; d += 256) {
      float pe = 0.f;
      if (d < 500) {
        int i = (d < 250) ? d : d - 250;
        float ang = fp * expf((float)i * -0.036989318762956f); // -ln(10000)/249
        pe = (d < 250) ? sinf(ang) : cosf(ang);
      }
      PE[t * 512 + d] = pe;
    }
    return;
  }
  bx -= 512;
  int e = bx * 256 + threadIdx.x;
  if (e < 1536) {
    float f = 0.f;
    if (e < 1500) {
      f = inb[e];
      if (e < 500) f *= 0.14142135623730951f;
    }
    INB[e] = f;
  }
}

// ---------------- positional embedding + add (table lookup, no trig) ----------------
__global__ __launch_bounds__(256) void posemb(const int* __restrict__ ori, const float* __restrict__ x,
                                              const float* __restrict__ PE, u16* __restrict__ out) {
  int m = blockIdx.x;
  int t = m & 511;
  bool np = (ori[m] != 0);
  for (int d = threadIdx.x; d < 512; d += 256) {
    float v = 0.f;
    if (d < 500) {
      float pe = np ? PE[t * 512 + d] : 0.f;
      v = pe + x[(size_t)m * 500 + d];
    }
    out[(size_t)m * 512 + d] = f2b(v);
  }
}

// ---------------- depthwise conv (k=7, pad=3) along T ----------------
__global__ __launch_bounds__(256) void dwconv(const u16* __restrict__ X, const float* __restrict__ dw,
                                              const float* __restrict__ db, u16* __restrict__ Y) {
  int b = blockIdx.y;
  int t0 = blockIdx.x * 8;
  int c0 = (threadIdx.x & 127) * 4;  // channel base (0..508)
  int ts = threadIdx.x >> 7;         // 0..1
  int tb = t0 + ts * 4;              // first output t (consecutive 4)

  float wv[7][4];
  float bias[4];
#pragma unroll
  for (int j = 0; j < 4; j++) {
    int c = c0 + j;
    bool ok = (c < 500);
    bias[j] = ok ? db[c] : 0.f;
#pragma unroll
    for (int k = 0; k < 7; k++) wv[k][j] = ok ? dw[c * 7 + k] : 0.f;
  }

  const u16* Xb = X + (size_t)b * 512 * 512 + c0;
  u16* Yb = Y + (size_t)b * 512 * 512 + c0;

  u16x4 xr[10];
#pragma unroll
  for (int k = 0; k < 10; k++) {
    int tt = tb - 3 + k;
    u16x4 z = {0, 0, 0, 0};
    xr[k] = (tt >= 0 && tt < 512) ? *(const u16x4*)(Xb + (size_t)tt * 512) : z;
  }

#pragma unroll
  for (int it = 0; it < 4; it++) {
    float acc[4] = {bias[0], bias[1], bias[2], bias[3]};
#pragma unroll
    for (int k = 0; k < 7; k++)
#pragma unroll
      for (int j = 0; j < 4; j++)
        acc[j] += wv[k][j] * b2f(xr[it + k][j]);
    u16x4 o;
#pragma unroll
    for (int j = 0; j < 4; j++) o[j] = f2b(acc[j]);
    *(u16x4*)(Yb + (size_t)(tb + it) * 512) = o;
  }
}

// ---------------- GEMM: out[m][n] = sum_k A[m][k]*W[n][k] + bias + res ----------------
// BK=64, XOR-swizzled staging (rule 21: pre-swizzled global source + same XOR on read).
__global__ __launch_bounds__(256) void gemm_bt(const u16* __restrict__ A, const u16* __restrict__ W,
                                               const float* __restrict__ bias, int nbias,
                                               const u16* __restrict__ res,
                                               u16* __restrict__ outb, float* __restrict__ outf,
                                               int ldo, int nstore) {
  union SM {
    struct { u16 A[2][8192]; u16 B[2][8192]; } s;  // 64 KB staging (double-buffered, BK=64)
    float o[64 * 132];                             // 33.8 KB epilogue half-tile
  };
  __shared__ __align__(16) SM sm;

  int tid = threadIdx.x;
  int m0 = blockIdx.x * 128;
  int n0 = blockIdx.y * 128;
  int lane = tid & 63, w = tid >> 6;
  int wm = (w & 1) * 64, wn = (w >> 1) * 64;
  int lr = lane & 15, kg = lane >> 4;

  f32x4 acc[4][4] = {};
  int srow = tid >> 3;
  int srcc = (tid & 7) ^ (srow & 7);
  const u16* ga = A + (size_t)(m0 + srow) * 512 + srcc * 8;
  const u16* gb = W + (size_t)(n0 + srow) * 512 + srcc * 8;

  auto STAGE = [&](int buf, int kk) {
    const u16* ga0 = ga + kk * 64;
    const u16* gb0 = gb + kk * 64;
#pragma unroll
    for (int p = 0; p < 4; p++) {
      async16(ga0 + (size_t)p * 32 * 512, sm.s.A[buf] + tid * 8 + p * 2048);
      async16(gb0 + (size_t)p * 32 * 512, sm.s.B[buf] + tid * 8 + p * 2048);
    }
  };
  auto COMPUTE = [&](int buf) {
    bf16x8 af[2][4], bfr[2][4];
#pragma unroll
    for (int ks = 0; ks < 2; ks++) {
#pragma unroll
      for (int i = 0; i < 4; i++)
        af[ks][i] = *(const bf16x8*)(sm.s.A[buf] + (wm + i * 16 + lr) * 64 +
                                     (((ks * 4 + kg) ^ (lr & 7)) * 8));
#pragma unroll
      for (int j = 0; j < 4; j++)
        bfr[ks][j] = *(const bf16x8*)(sm.s.B[buf] + (wn + j * 16 + lr) * 64 +
                                      (((ks * 4 + kg) ^ (lr & 7)) * 8));
    }
#pragma unroll
    for (int ks = 0; ks < 2; ks++)
#pragma unroll
      for (int i = 0; i < 4; i++)
#pragma unroll
        for (int j = 0; j < 4; j++) acc[i][j] = MFMA16(af[ks][i], bfr[ks][j], acc[i][j]);
  };

  STAGE(0, 0);
  drain_vm();
  __syncthreads();
#pragma unroll
  for (int kk = 0; kk < 8; kk++) {
    if (kk < 7) STAGE((kk + 1) & 1, kk + 1);   // prefetch next K-block
    COMPUTE(kk & 1);
    drain_vm();                                 // next buf's LDS writes landed
    __syncthreads();
  }

  // ---- epilogue: two row-halves through LDS, coalesced global I/O ----
#pragma unroll
  for (int half = 0; half < 2; half++) {
    if ((w & 1) == half) {
#pragma unroll
      for (int i = 0; i < 4; i++)
#pragma unroll
        for (int j = 0; j < 4; j++) {
          int gn = n0 + wn + j * 16 + lr;
          float bv = (gn < nbias) ? bias[gn] : 0.f;
#pragma unroll
          for (int r = 0; r < 4; r++)
            sm.o[(i * 16 + kg * 4 + r) * 132 + wn + j * 16 + lr] = acc[i][j][r] + bv;
        }
    }
    __syncthreads();
    int rl = tid >> 4;
    int colv = (tid & 15) * 8;
#pragma unroll
    for (int p = 0; p < 4; p++) {
      int rrow = rl + p * 16;
      int m = m0 + half * 64 + rrow;
      const float* lp = sm.o + rrow * 132 + colv;
      f32x4 v0 = *(const f32x4*)lp;
      f32x4 v1 = *(const f32x4*)(lp + 4);
      if (res != nullptr) {
        u16x8 rv = *(const u16x8*)(res + (size_t)m * 512 + n0 + colv);
#pragma unroll
        for (int k = 0; k < 4; k++) { v0[k] += b2f(rv[k]); v1[k] += b2f(rv[4 + k]); }
      }
      if (outf != nullptr) {
        int gc = n0 + colv;
        if (gc + 4 <= nstore) *(f32x4*)(outf + (size_t)m * ldo + gc) = v0;
        if (gc + 8 <= nstore) *(f32x4*)(outf + (size_t)m * ldo + gc + 4) = v1;
      } else {
        u16x8 ov;
#pragma unroll
        for (int k = 0; k < 4; k++) { ov[k] = f2b(v0[k]); ov[4 + k] = f2b(v1[k]); }
        *(u16x8*)(outb + (size_t)m * ldo + n0 + colv) = ov;
      }
    }
    __syncthreads();
  }
}

// ---------------- QKV GEMM with head-separated scatter epilogue ----------------
// R11-proven loop: BK=32, 3-buffer, counted vmcnt(4) (the BK=64 2-buffer port
// raced nondeterministically in R12 with zero speed benefit — reverted).
// Epilogue: V-segment stores vectorized (r -> consecutive t -> one u16x4);
// address math proven by R12's passing first-check.
__global__ __launch_bounds__(256) void gemm_qkv(const u16* __restrict__ A, const u16* __restrict__ W,
                                                const float* __restrict__ bias, u16* __restrict__ out) {
  __shared__ __align__(16) u16 As[3][128 * 32];
  __shared__ __align__(16) u16 Bs[3][128 * 32];
  int tid = threadIdx.x;
  int m0 = blockIdx.x * 128;
  int n0 = blockIdx.y * 128;
  int lane = tid & 63, w = tid >> 6;
  int wm = (w & 1) * 64, wn = (w >> 1) * 64;
  int lr = lane & 15, kg = lane >> 4;

  f32x4 acc[4][4] = {};
  int row = tid >> 2, sub = tid & 3;
  const u16* ga = A + (size_t)(m0 + row) * 512 + sub * 8;
  const u16* gb = W + (size_t)(n0 + row) * 512 + sub * 8;

  auto STAGE = [&](int buf, int kk) {
    const u16* ga0 = ga + kk * 32;
    const u16* gb0 = gb + kk * 32;
    async16(ga0, As[buf] + tid * 8);
    async16(ga0 + 64 * 512, As[buf] + 2048 + tid * 8);
    async16(gb0, Bs[buf] + tid * 8);
    async16(gb0 + 64 * 512, Bs[buf] + 2048 + tid * 8);
  };
  auto COMPUTE = [&](int buf) {
    bf16x8 af[4], bfr[4];
#pragma unroll
    for (int i = 0; i < 4; i++) af[i] = *(const bf16x8*)(As[buf] + (wm + i * 16 + lr) * 32 + kg * 8);
#pragma unroll
    for (int j = 0; j < 4; j++) bfr[j] = *(const bf16x8*)(Bs[buf] + (wn + j * 16 + lr) * 32 + kg * 8);
#pragma unroll
    for (int i = 0; i < 4; i++)
#pragma unroll
      for (int j = 0; j < 4; j++) acc[i][j] = MFMA16(af[i], bfr[j], acc[i][j]);
  };

  STAGE(0, 0);
  STAGE(1, 1);
#pragma unroll
  for (int kk = 0; kk < 16; kk++) {
    if (kk < 15) wait_vm4();
    else         drain_vm();
    __builtin_amdgcn_sched_barrier(0);
    __syncthreads();
    if (kk + 2 < 16) STAGE((kk + 2) % 3, kk + 2);
    COMPUTE(kk % 3);
  }

#pragma unroll
  for (int i = 0; i < 4; i++) {
#pragma unroll
    for (int j = 0; j < 4; j++) {
      int n = n0 + wn + j * 16 + lr;
      if (n >= 1500) continue;
      int sel = n / 500;
      int rem = n - sel * 500;
      int head = rem / 50;
      int hd = rem - head * 50;
      float bv = bias[n];
      int mb = m0 + wm + i * 16 + kg * 4;    // first of 4 consecutive m (mult of 4)
      int bl = mb >> 9, t0 = mb & 511;
      size_t base = ((size_t)(bl * 10 + head) * 3 + sel) * 32768;
      if (sel < 2) {
#pragma unroll
        for (int r = 0; r < 4; r++)
          out[base + (t0 + r) * 64 + hd] = f2b(acc[i][j][r] + bv);
      } else {
        u16x4 v4 = {f2b(acc[i][j][0] + bv), f2b(acc[i][j][1] + bv),
                    f2b(acc[i][j][2] + bv), f2b(acc[i][j][3] + bv)};
        *(u16x4*)(out + base + (size_t)hd * 512 + t0) = v4;
      }
    }
  }
}

// ---------------- fused attention (flash-style, online softmax) ----------------
// SWAPPED QK^T (mfma(K,Q)): C col=lane&15 = q, row = k -> each lane holds 16
// S-values of ONE q-row. Row max/sum become in-register VALU trees + 2 shfls.
static constexpr int LP = 72;
__global__ __launch_bounds__(256) void attn(const u16* __restrict__ qkv, u16* __restrict__ att) {
  __shared__ __align__(16) u16 Qs[64 * LP];
  __shared__ __align__(16) u16 Ks[64 * LP];
  __shared__ __align__(16) u16 Vs[64 * LP];  // Vt[hd][t-within-tile]
  __shared__ __align__(16) u16 Ps[64 * LP];
  __shared__ __align__(16) float Al[4][16];  // per-wave alpha / li broadcast
  int tid = threadIdx.x;
  int qt = blockIdx.x, h = blockIdx.y, b = blockIdx.z;
  const u16* baseQ = qkv + ((size_t)(b * 10 + h) * 3 + 0) * 32768;
  const u16* baseK = baseQ + 32768;
  const u16* baseV = baseQ + 2 * 32768;

  int r0 = tid >> 3, cg = tid & 7;

  u32x4 kreg0, kreg1, vreg0, vreg1;
  auto LOADKV = [&](int kt) {
    const u16* pk = baseK + kt * 4096;
    const u16* pv = baseV + kt * 64;
    u32x4 z = {0, 0, 0, 0};
    kreg0 = (cg < 7) ? *(const u32x4*)(pk + r0 * 64 + cg * 8) : z;
    kreg1 = (cg < 7) ? *(const u32x4*)(pk + (r0 + 32) * 64 + cg * 8) : z;
    vreg0 = *(const u32x4*)(pv + (size_t)r0 * 512 + cg * 8);
    vreg1 = *(const u32x4*)(pv + (size_t)(r0 + 32) * 512 + cg * 8);
  };
  auto WRITEKV = [&]() {
    u32x4 k0 = kreg0, k1 = kreg1;
    if (cg == 6) { k0[1] = 0; k0[2] = 0; k0[3] = 0; k1[1] = 0; k1[2] = 0; k1[3] = 0; }
    *(u32x4*)(Ks + r0 * LP + cg * 8) = k0;
    *(u32x4*)(Ks + (r0 + 32) * LP + cg * 8) = k1;
    *(u32x4*)(Vs + r0 * LP + cg * 8) = vreg0;
    *(u32x4*)(Vs + (r0 + 32) * LP + cg * 8) = vreg1;
  };

  LOADKV(0);   // in flight during Q staging

#pragma unroll
  for (int ii = 0; ii < 2; ii++) {
    int rr = r0 + ii * 32;
    u32x4 qv = {0, 0, 0, 0};
    if (cg < 7) qv = *(const u32x4*)(baseQ + qt * 4096 + rr * 64 + cg * 8);
    if (cg == 6) { qv[1] = 0; qv[2] = 0; qv[3] = 0; }
    *(u32x4*)(Qs + rr * LP + cg * 8) = qv;
  }
  __syncthreads();

  int lane = tid & 63, w = tid >> 6, lr = lane & 15, kg = lane >> 4;
  // Q as B-operand (lane&15 = q-col)
  bf16x8 bq0 = *(const bf16x8*)(Qs + (w * 16 + lr) * LP + kg * 8);
  bf16x8 bq1 = *(const bf16x8*)(Qs + (w * 16 + lr) * LP + 32 + kg * 8);

  f32x4 O[4] = {};
  float mi = -__builtin_inff();   // running max for q = w*16+lr (dup across kg)
  float li = 0.f;                 // running sum for q = w*16+lr

  for (int kt = 0; kt < 8; kt++) {
    WRITEKV();
    if (kt < 7) LOADKV(kt + 1);
    __syncthreads();

    // S^T = K Q^T: lane holds S[q=w*16+lr][k=j*16+kg*4+rg]
    f32x4 s[4];
#pragma unroll
    for (int j = 0; j < 4; j++) {
      bf16x8 ak0 = *(const bf16x8*)(Ks + (j * 16 + lr) * LP + kg * 8);
      bf16x8 ak1 = *(const bf16x8*)(Ks + (j * 16 + lr) * LP + 32 + kg * 8);
      f32x4 z = {0.f, 0.f, 0.f, 0.f};
      z = MFMA16(ak0, bq0, z);
      z = MFMA16(ak1, bq1, z);
      s[j] = z;
    }

    // in-register row reduction (16 values) + 2 cross-group shfls
    f32x4 m4 = s[0];
#pragma unroll
    for (int j = 1; j < 4; j++)
#pragma unroll
      for (int rg = 0; rg < 4; rg++) m4[rg] = fmaxf(m4[rg], s[j][rg]);
    float mx = fmaxf(fmaxf(m4[0], m4[1]), fmaxf(m4[2], m4[3]));
    mx = fmaxf(mx, __shfl_xor(mx, 16));
    mx = fmaxf(mx, __shfl_xor(mx, 32));

    float mn = fmaxf(mi, mx);
    float alpha = __expf(mi - mn);
#pragma unroll
    for (int j = 0; j < 4; j++)
#pragma unroll
      for (int rg = 0; rg < 4; rg++) s[j][rg] = __expf(s[j][rg] - mn);
    f32x4 s4 = s[0];
#pragma unroll
    for (int j = 1; j < 4; j++)
#pragma unroll
      for (int rg = 0; rg < 4; rg++) s4[rg] += s[j][rg];
    float rs = (s4[0] + s4[1]) + (s4[2] + s4[3]);
    rs += __shfl_xor(rs, 16);
    rs += __shfl_xor(rs, 32);
    li = li * alpha + rs;
    mi = mn;

    // packed P write: rg are consecutive k -> u16x4 per j
#pragma unroll
    for (int j = 0; j < 4; j++) {
      u16x4 pv4 = {f2b(s[j][0]), f2b(s[j][1]), f2b(s[j][2]), f2b(s[j][3])};
      *(u16x4*)(Ps + (w * 16 + lr) * LP + j * 16 + kg * 4) = pv4;
    }

    // broadcast alpha (per q=lr) to O-layout rows (q=kg*4+rg)
    if (kg == 0) Al[w][lr] = alpha;
    f32x4 av = *(const f32x4*)&Al[w][kg * 4];
#pragma unroll
    for (int sb = 0; sb < 4; sb++)
#pragma unroll
      for (int rg = 0; rg < 4; rg++) O[sb][rg] *= av[rg];

    // PV (forward): A = P rows, B = V^T rows
    bf16x8 ap0 = *(const bf16x8*)(Ps + (w * 16 + lr) * LP + kg * 8);
    bf16x8 ap1 = *(const bf16x8*)(Ps + (w * 16 + lr) * LP + 32 + kg * 8);
#pragma unroll
    for (int sb = 0; sb < 4; sb++) {
      bf16x8 bv0 = *(const bf16x8*)(Vs + (sb * 16 + lr) * LP + kg * 8);
      bf16x8 bv1 = *(const bf16x8*)(Vs + (sb * 16 + lr) * LP + 32 + kg * 8);
      O[sb] = MFMA16(ap0, bv0, O[sb]);
      O[sb] = MFMA16(ap1, bv1, O[sb]);
    }
    __syncthreads();               // Ks/Vs reads done before next WRITEKV
  }

  // broadcast final li to O-layout rows
  if (kg == 0) Al[w][lr] = li;
  f32x4 lv = *(const f32x4*)&Al[w][kg * 4];

#pragma unroll
  for (int rg = 0; rg < 4; rg++) {
    float inv = 1.f / lv[rg];
    int t = qt * 64 + w * 16 + kg * 4 + rg;
    size_t rowbase = ((size_t)b * 512 + t) * 512;
#pragma unroll
    for (int sb = 0; sb < 4; sb++) {
      int hd = sb * 16 + lr;
      if (hd < 50)
        att[rowbase + h * 50 + hd] = f2b(O[sb][rg] * inv);
      else if (h == 9 && hd < 62)
        att[rowbase + 450 + hd] = 0;   // zero att pad cols 500..511
    }
  }
}

// ---------------- workspace layout (~114 MiB of the ~268 MiB ws) ----------------
static constexpr size_t MB = 1024 * 1024;
static constexpr size_t OFF_S0  = 0;                      // [0,16M)    x0 / out3 (bf16)
static constexpr size_t OFF_S1  = 16 * MB;                // [16M,32M)  ping-pong, then ATT
static constexpr size_t OFF_R   = 32 * MB;                // [32M,48M)  DW scratch -> OUT4
static constexpr size_t OFF_QKV = 48 * MB;                // [48M,108M) full head-separated QKV (60 MB)
static constexpr size_t OFF_PE  = 108 * MB;               // f32[512*512] (1 MB)
static constexpr size_t OFF_PW  = 109 * MB;
static constexpr size_t SZ_W = (size_t)512 * 512 * 2;
static constexpr size_t OFF_OW = OFF_PW + 4 * SZ_W;
static constexpr size_t OFF_FW = OFF_OW + SZ_W;
static constexpr size_t OFF_INW = OFF_FW + SZ_W;
static constexpr size_t OFF_INB = OFF_INW + (size_t)1536 * 512 * 2;   // f32[1536]

extern "C" void kernel_launch(void* const* d_in, const int* in_sizes, int n_in,
                              void* d_out, int out_size, void* d_ws, size_t ws_size,
                              hipStream_t stream) {
  const int* ori = (const int*)d_in[0];
  const float* x = (const float*)d_in[1];
  const float* dwv[4] = {(const float*)d_in[3], (const float*)d_in[7], (const float*)d_in[11], (const float*)d_in[15]};
  const float* dbv[4] = {(const float*)d_in[4], (const float*)d_in[8], (const float*)d_in[12], (const float*)d_in[16]};
  const float* pwv[4] = {(const float*)d_in[5], (const float*)d_in[9], (const float*)d_in[13], (const float*)d_in[17]};
  const float* pbv[4] = {(const float*)d_in[6], (const float*)d_in[10], (const float*)d_in[14], (const float*)d_in[18]};
  const float* in_w = (const float*)d_in[19];
  const float* in_b = (const float*)d_in[20];
  const float* out_w = (const float*)d_in[21];
  const float* out_b = (const float*)d_in[22];
  const float* ffc_w = (const float*)d_in[23];
  const float* ffc_b = (const float*)d_in[24];

  char* ws = (char*)d_ws;
  u16* S0  = (u16*)(ws + OFF_S0);
  u16* S1  = (u16*)(ws + OFF_S1);
  u16* R   = (u16*)(ws + OFF_R);
  u16* QKV = (u16*)(ws + OFF_QKV);
  float* PE = (float*)(ws + OFF_PE);
  u16* PW  = (u16*)(ws + OFF_PW);
  u16* OW  = (u16*)(ws + OFF_OW);
  u16* FW  = (u16*)(ws + OFF_FW);
  u16* INW = (u16*)(ws + OFF_INW);
  float* INB = (float*)(ws + OFF_INB);

  // all weight packing + PE table in one launch
  packall<<<5126, 256, 0, stream>>>(pwv[0], pwv[1], pwv[2], pwv[3], out_w, ffc_w, in_w, in_b,
                                    PW, OW, FW, INW, INB, PE);

  // x0 = pos_emb + x (table lookup)
  posemb<<<M, 256, 0, stream>>>(ori, x, PE, S0);

  // 4x sepconv + residual (DW scratch in R)
  u16* cur = S0;
  u16* nxt = S1;
  for (int i = 0; i < 4; i++) {
    dwconv<<<dim3(64, 32), 256, 0, stream>>>(cur, dwv[i], dbv[i], R);
    gemm_bt<<<dim3(128, 4), 256, 0, stream>>>(R, PW + (size_t)i * 512 * 512, pbv[i], 500,
                                              cur, nxt, nullptr, 512, 512);
    u16* t2 = cur; cur = nxt; nxt = t2;
  }
  // cur == S0 holds out3; S1 free

  // qkv projection (full batch) + attention (full batch); ATT = S1
  gemm_qkv<<<dim3(128, 12), 256, 0, stream>>>(cur, INW, INB, QKV);
  attn<<<dim3(8, 10, 32), 256, 0, stream>>>(QKV, S1);

  // out_proj + residual(out3=S0) -> OUT4 in R
  gemm_bt<<<dim3(128, 4), 256, 0, stream>>>(S1, OW, out_b, 500, cur, R, nullptr, 512, 512);

  // ffc + residual(OUT4) -> d_out f32 [M][500]
  gemm_bt<<<dim3(128, 4), 256, 0, stream>>>(R, FW, ffc_b, 500, R, nullptr, (float*)d_out, 500, 500);
}

// Round 14
// 428.596 us; speedup vs baseline: 1.1153x; 1.0392x over previous
//
#include <hip/hip_runtime.h>
#include <cstdint>
#include <cstddef>

typedef unsigned short u16;
typedef __bf16 bf16x8 __attribute__((ext_vector_type(8)));
typedef float f32x4 __attribute__((ext_vector_type(4)));
typedef unsigned int u32;
typedef u32 u32x4 __attribute__((ext_vector_type(4)));
typedef u16 u16x8 __attribute__((ext_vector_type(8)));
typedef u16 u16x4 __attribute__((ext_vector_type(4)));

#define MFMA16(a, b, c) __builtin_amdgcn_mfma_f32_16x16x32_bf16((a), (b), (c), 0, 0, 0)

static constexpr int B = 32, T = 512, D = 500, H = 10, HD = 50;
static constexpr int M = B * T;          // 16384 tokens

__device__ __forceinline__ float b2f(u16 u) { return (float)__builtin_bit_cast(__bf16, u); }
__device__ __forceinline__ u16 f2b(float f) { return __builtin_bit_cast(u16, (__bf16)f); }

__device__ __forceinline__ void async16(const void* g, void* s) {
  __builtin_amdgcn_global_load_lds((const __attribute__((address_space(1))) void*)g,
                                   (__attribute__((address_space(3))) void*)s, 16, 0, 0);
}

__device__ __forceinline__ void wait_vm4() {
  asm volatile("s_waitcnt vmcnt(4)" ::: "memory");
}
__device__ __forceinline__ void drain_vm() {
  asm volatile("s_waitcnt vmcnt(0)" ::: "memory");
}

// ---------------- all weight packing + PE table in ONE kernel ----------------
__global__ __launch_bounds__(256) void packall(
    const float* __restrict__ pw0, const float* __restrict__ pw1,
    const float* __restrict__ pw2, const float* __restrict__ pw3,
    const float* __restrict__ ow, const float* __restrict__ fw,
    const float* __restrict__ inw, const float* __restrict__ inb,
    u16* __restrict__ PW, u16* __restrict__ OW, u16* __restrict__ FW,
    u16* __restrict__ INW, float* __restrict__ INB, float* __restrict__ PE) {
  int bx = blockIdx.x;
  if (bx < 3072) {
    int which = bx >> 9, o = bx & 511;
    const float* src = which == 0 ? pw0 : which == 1 ? pw1 : which == 2 ? pw2
                     : which == 3 ? pw3 : which == 4 ? ow : fw;
    u16* dst = which < 4 ? PW + (size_t)which * 512 * 512 : (which == 4 ? OW : FW);
    for (int c = threadIdx.x; c < 512; c += 256)
      dst[o * 512 + c] = (o < 500 && c < 500) ? f2b(src[o * 500 + c]) : (u16)0;
    return;
  }
  bx -= 3072;
  if (bx < 1536) {
    int e = bx;
    for (int c = threadIdx.x; c < 512; c += 256) {
      u16 v = 0;
      if (e < 1500 && c < 500) {
        float f = inw[e * 500 + c];
        if (e < 500) f *= 0.14142135623730951f;
        v = f2b(f);
      }
      INW[e * 512 + c] = v;
    }
    return;
  }
  bx -= 1536;
  if (bx < 512) {
    int t = bx;
    float fp = (float)(t + 1);
    for (int d = threadIdx.x; d < 512; d += 256) {
      float pe = 0.f;
      if (d < 500) {
        int i = (d < 250) ? d : d - 250;
        float ang = fp * expf((float)i * -0.036989318762956f); // -ln(10000)/249
        pe = (d < 250) ? sinf(ang) : cosf(ang);
      }
      PE[t * 512 + d] = pe;
    }
    return;
  }
  bx -= 512;
  int e = bx * 256 + threadIdx.x;
  if (e < 1536) {
    float f = 0.f;
    if (e < 1500) {
      f = inb[e];
      if (e < 500) f *= 0.14142135623730951f;
    }
    INB[e] = f;
  }
}

// ---------------- positional embedding + add (table lookup, no trig) ----------------
__global__ __launch_bounds__(256) void posemb(const int* __restrict__ ori, const float* __restrict__ x,
                                              const float* __restrict__ PE, u16* __restrict__ out) {
  int m = blockIdx.x;
  int t = m & 511;
  bool np = (ori[m] != 0);
  for (int d = threadIdx.x; d < 512; d += 256) {
    float v = 0.f;
    if (d < 500) {
      float pe = np ? PE[t * 512 + d] : 0.f;
      v = pe + x[(size_t)m * 500 + d];
    }
    out[(size_t)m * 512 + d] = f2b(v);
  }
}

// ---------------- depthwise conv (k=7, pad=3) along T ----------------
__global__ __launch_bounds__(256) void dwconv(const u16* __restrict__ X, const float* __restrict__ dw,
                                              const float* __restrict__ db, u16* __restrict__ Y) {
  int b = blockIdx.y;
  int t0 = blockIdx.x * 8;
  int c0 = (threadIdx.x & 127) * 4;  // channel base (0..508)
  int ts = threadIdx.x >> 7;         // 0..1
  int tb = t0 + ts * 4;              // first output t (consecutive 4)

  float wv[7][4];
  float bias[4];
#pragma unroll
  for (int j = 0; j < 4; j++) {
    int c = c0 + j;
    bool ok = (c < 500);
    bias[j] = ok ? db[c] : 0.f;
#pragma unroll
    for (int k = 0; k < 7; k++) wv[k][j] = ok ? dw[c * 7 + k] : 0.f;
  }

  const u16* Xb = X + (size_t)b * 512 * 512 + c0;
  u16* Yb = Y + (size_t)b * 512 * 512 + c0;

  u16x4 xr[10];
#pragma unroll
  for (int k = 0; k < 10; k++) {
    int tt = tb - 3 + k;
    u16x4 z = {0, 0, 0, 0};
    xr[k] = (tt >= 0 && tt < 512) ? *(const u16x4*)(Xb + (size_t)tt * 512) : z;
  }

#pragma unroll
  for (int it = 0; it < 4; it++) {
    float acc[4] = {bias[0], bias[1], bias[2], bias[3]};
#pragma unroll
    for (int k = 0; k < 7; k++)
#pragma unroll
      for (int j = 0; j < 4; j++)
        acc[j] += wv[k][j] * b2f(xr[it + k][j]);
    u16x4 o;
#pragma unroll
    for (int j = 0; j < 4; j++) o[j] = f2b(acc[j]);
    *(u16x4*)(Yb + (size_t)(tb + it) * 512) = o;
  }
}

// ---------------- GEMM: out[m][n] = sum_k A[m][k]*W[n][k] + bias + res ----------------
// BK=64, XOR-swizzled staging (rule 21: pre-swizzled global source + same XOR on read).
__global__ __launch_bounds__(256) void gemm_bt(const u16* __restrict__ A, const u16* __restrict__ W,
                                               const float* __restrict__ bias, int nbias,
                                               const u16* __restrict__ res,
                                               u16* __restrict__ outb, float* __restrict__ outf,
                                               int ldo, int nstore) {
  union SM {
    struct { u16 A[2][8192]; u16 B[2][8192]; } s;  // 64 KB staging (double-buffered, BK=64)
    float o[64 * 132];                             // 33.8 KB epilogue half-tile
  };
  __shared__ __align__(16) SM sm;

  int tid = threadIdx.x;
  int m0 = blockIdx.x * 128;
  int n0 = blockIdx.y * 128;
  int lane = tid & 63, w = tid >> 6;
  int wm = (w & 1) * 64, wn = (w >> 1) * 64;
  int lr = lane & 15, kg = lane >> 4;

  f32x4 acc[4][4] = {};
  int srow = tid >> 3;
  int srcc = (tid & 7) ^ (srow & 7);
  const u16* ga = A + (size_t)(m0 + srow) * 512 + srcc * 8;
  const u16* gb = W + (size_t)(n0 + srow) * 512 + srcc * 8;

  auto STAGE = [&](int buf, int kk) {
    const u16* ga0 = ga + kk * 64;
    const u16* gb0 = gb + kk * 64;
#pragma unroll
    for (int p = 0; p < 4; p++) {
      async16(ga0 + (size_t)p * 32 * 512, sm.s.A[buf] + tid * 8 + p * 2048);
      async16(gb0 + (size_t)p * 32 * 512, sm.s.B[buf] + tid * 8 + p * 2048);
    }
  };
  auto COMPUTE = [&](int buf) {
    bf16x8 af[2][4], bfr[2][4];
#pragma unroll
    for (int ks = 0; ks < 2; ks++) {
#pragma unroll
      for (int i = 0; i < 4; i++)
        af[ks][i] = *(const bf16x8*)(sm.s.A[buf] + (wm + i * 16 + lr) * 64 +
                                     (((ks * 4 + kg) ^ (lr & 7)) * 8));
#pragma unroll
      for (int j = 0; j < 4; j++)
        bfr[ks][j] = *(const bf16x8*)(sm.s.B[buf] + (wn + j * 16 + lr) * 64 +
                                      (((ks * 4 + kg) ^ (lr & 7)) * 8));
    }
#pragma unroll
    for (int ks = 0; ks < 2; ks++)
#pragma unroll
      for (int i = 0; i < 4; i++)
#pragma unroll
        for (int j = 0; j < 4; j++) acc[i][j] = MFMA16(af[ks][i], bfr[ks][j], acc[i][j]);
  };

  STAGE(0, 0);
  drain_vm();
  __syncthreads();
#pragma unroll
  for (int kk = 0; kk < 8; kk++) {
    if (kk < 7) STAGE((kk + 1) & 1, kk + 1);   // prefetch next K-block
    COMPUTE(kk & 1);
    drain_vm();                                 // next buf's LDS writes landed
    __syncthreads();
  }

  // ---- epilogue: two row-halves through LDS, coalesced global I/O ----
#pragma unroll
  for (int half = 0; half < 2; half++) {
    if ((w & 1) == half) {
#pragma unroll
      for (int i = 0; i < 4; i++)
#pragma unroll
        for (int j = 0; j < 4; j++) {
          int gn = n0 + wn + j * 16 + lr;
          float bv = (gn < nbias) ? bias[gn] : 0.f;
#pragma unroll
          for (int r = 0; r < 4; r++)
            sm.o[(i * 16 + kg * 4 + r) * 132 + wn + j * 16 + lr] = acc[i][j][r] + bv;
        }
    }
    __syncthreads();
    int rl = tid >> 4;
    int colv = (tid & 15) * 8;
#pragma unroll
    for (int p = 0; p < 4; p++) {
      int rrow = rl + p * 16;
      int m = m0 + half * 64 + rrow;
      const float* lp = sm.o + rrow * 132 + colv;
      f32x4 v0 = *(const f32x4*)lp;
      f32x4 v1 = *(const f32x4*)(lp + 4);
      if (res != nullptr) {
        u16x8 rv = *(const u16x8*)(res + (size_t)m * 512 + n0 + colv);
#pragma unroll
        for (int k = 0; k < 4; k++) { v0[k] += b2f(rv[k]); v1[k] += b2f(rv[4 + k]); }
      }
      if (outf != nullptr) {
        int gc = n0 + colv;
        if (gc + 4 <= nstore) *(f32x4*)(outf + (size_t)m * ldo + gc) = v0;
        if (gc + 8 <= nstore) *(f32x4*)(outf + (size_t)m * ldo + gc + 4) = v1;
      } else {
        u16x8 ov;
#pragma unroll
        for (int k = 0; k < 4; k++) { ov[k] = f2b(v0[k]); ov[4 + k] = f2b(v1[k]); }
        *(u16x8*)(outb + (size_t)m * ldo + n0 + colv) = ov;
      }
    }
    __syncthreads();
  }
}

// ---------------- QKV GEMM with head-separated scatter epilogue ----------------
// R11-proven loop: BK=32, 3-buffer, counted vmcnt(4). V-segment stores u16x4.
__global__ __launch_bounds__(256) void gemm_qkv(const u16* __restrict__ A, const u16* __restrict__ W,
                                                const float* __restrict__ bias, u16* __restrict__ out) {
  __shared__ __align__(16) u16 As[3][128 * 32];
  __shared__ __align__(16) u16 Bs[3][128 * 32];
  int tid = threadIdx.x;
  int m0 = blockIdx.x * 128;
  int n0 = blockIdx.y * 128;
  int lane = tid & 63, w = tid >> 6;
  int wm = (w & 1) * 64, wn = (w >> 1) * 64;
  int lr = lane & 15, kg = lane >> 4;

  f32x4 acc[4][4] = {};
  int row = tid >> 2, sub = tid & 3;
  const u16* ga = A + (size_t)(m0 + row) * 512 + sub * 8;
  const u16* gb = W + (size_t)(n0 + row) * 512 + sub * 8;

  auto STAGE = [&](int buf, int kk) {
    const u16* ga0 = ga + kk * 32;
    const u16* gb0 = gb + kk * 32;
    async16(ga0, As[buf] + tid * 8);
    async16(ga0 + 64 * 512, As[buf] + 2048 + tid * 8);
    async16(gb0, Bs[buf] + tid * 8);
    async16(gb0 + 64 * 512, Bs[buf] + 2048 + tid * 8);
  };
  auto COMPUTE = [&](int buf) {
    bf16x8 af[4], bfr[4];
#pragma unroll
    for (int i = 0; i < 4; i++) af[i] = *(const bf16x8*)(As[buf] + (wm + i * 16 + lr) * 32 + kg * 8);
#pragma unroll
    for (int j = 0; j < 4; j++) bfr[j] = *(const bf16x8*)(Bs[buf] + (wn + j * 16 + lr) * 32 + kg * 8);
#pragma unroll
    for (int i = 0; i < 4; i++)
#pragma unroll
      for (int j = 0; j < 4; j++) acc[i][j] = MFMA16(af[i], bfr[j], acc[i][j]);
  };

  STAGE(0, 0);
  STAGE(1, 1);
#pragma unroll
  for (int kk = 0; kk < 16; kk++) {
    if (kk < 15) wait_vm4();
    else         drain_vm();
    __builtin_amdgcn_sched_barrier(0);
    __syncthreads();
    if (kk + 2 < 16) STAGE((kk + 2) % 3, kk + 2);
    COMPUTE(kk % 3);
  }

#pragma unroll
  for (int i = 0; i < 4; i++) {
#pragma unroll
    for (int j = 0; j < 4; j++) {
      int n = n0 + wn + j * 16 + lr;
      if (n >= 1500) continue;
      int sel = n / 500;
      int rem = n - sel * 500;
      int head = rem / 50;
      int hd = rem - head * 50;
      float bv = bias[n];
      int mb = m0 + wm + i * 16 + kg * 4;    // first of 4 consecutive m (mult of 4)
      int bl = mb >> 9, t0 = mb & 511;
      size_t base = ((size_t)(bl * 10 + head) * 3 + sel) * 32768;
      if (sel < 2) {
#pragma unroll
        for (int r = 0; r < 4; r++)
          out[base + (t0 + r) * 64 + hd] = f2b(acc[i][j][r] + bv);
      } else {
        u16x4 v4 = {f2b(acc[i][j][0] + bv), f2b(acc[i][j][1] + bv),
                    f2b(acc[i][j][2] + bv), f2b(acc[i][j][3] + bv)};
        *(u16x4*)(out + base + (size_t)hd * 512 + t0) = v4;
      }
    }
  }
}

// ---------------- fused attention (flash-style, online softmax) ----------------
// SWAPPED QK^T (R13-proven) + XCD-aware flat grid (R7-proven decode): the 8
// qt-siblings of one (b,h) share bx%8 (same XCD) and are 8 apart in dispatch
// order -> they consume the same K/V stream while L2-hot. Re-applied now that
// the VALU bottleneck is gone and attn runs at 2.9 TB/s (BW regime).
static constexpr int LP = 72;
__global__ __launch_bounds__(256) void attn(const u16* __restrict__ qkv, u16* __restrict__ att) {
  __shared__ __align__(16) u16 Qs[64 * LP];
  __shared__ __align__(16) u16 Ks[64 * LP];
  __shared__ __align__(16) u16 Vs[64 * LP];  // Vt[hd][t-within-tile]
  __shared__ __align__(16) u16 Ps[64 * LP];
  __shared__ __align__(16) float Al[4][16];  // per-wave alpha / li broadcast
  int tid = threadIdx.x;
  int bx = blockIdx.x;
  int r = bx & 7, s = bx >> 3;     // XCD residue, per-XCD sequence
  int qt = s & 7;                  // 8 siblings (qt 0..7) of one (b,h)
  int bh = (s >> 3) * 8 + r;       // 0..319, bijective over bx in [0,2560)
  int h = bh % 10, b = bh / 10;
  const u16* baseQ = qkv + ((size_t)(b * 10 + h) * 3 + 0) * 32768;
  const u16* baseK = baseQ + 32768;
  const u16* baseV = baseQ + 2 * 32768;

  int r0 = tid >> 3, cg = tid & 7;

  u32x4 kreg0, kreg1, vreg0, vreg1;
  auto LOADKV = [&](int kt) {
    const u16* pk = baseK + kt * 4096;
    const u16* pv = baseV + kt * 64;
    u32x4 z = {0, 0, 0, 0};
    kreg0 = (cg < 7) ? *(const u32x4*)(pk + r0 * 64 + cg * 8) : z;
    kreg1 = (cg < 7) ? *(const u32x4*)(pk + (r0 + 32) * 64 + cg * 8) : z;
    vreg0 = *(const u32x4*)(pv + (size_t)r0 * 512 + cg * 8);
    vreg1 = *(const u32x4*)(pv + (size_t)(r0 + 32) * 512 + cg * 8);
  };
  auto WRITEKV = [&]() {
    u32x4 k0 = kreg0, k1 = kreg1;
    if (cg == 6) { k0[1] = 0; k0[2] = 0; k0[3] = 0; k1[1] = 0; k1[2] = 0; k1[3] = 0; }
    *(u32x4*)(Ks + r0 * LP + cg * 8) = k0;
    *(u32x4*)(Ks + (r0 + 32) * LP + cg * 8) = k1;
    *(u32x4*)(Vs + r0 * LP + cg * 8) = vreg0;
    *(u32x4*)(Vs + (r0 + 32) * LP + cg * 8) = vreg1;
  };

  LOADKV(0);   // in flight during Q staging

#pragma unroll
  for (int ii = 0; ii < 2; ii++) {
    int rr = r0 + ii * 32;
    u32x4 qv = {0, 0, 0, 0};
    if (cg < 7) qv = *(const u32x4*)(baseQ + qt * 4096 + rr * 64 + cg * 8);
    if (cg == 6) { qv[1] = 0; qv[2] = 0; qv[3] = 0; }
    *(u32x4*)(Qs + rr * LP + cg * 8) = qv;
  }
  __syncthreads();

  int lane = tid & 63, w = tid >> 6, lr = lane & 15, kg = lane >> 4;
  // Q as B-operand (lane&15 = q-col)
  bf16x8 bq0 = *(const bf16x8*)(Qs + (w * 16 + lr) * LP + kg * 8);
  bf16x8 bq1 = *(const bf16x8*)(Qs + (w * 16 + lr) * LP + 32 + kg * 8);

  f32x4 O[4] = {};
  float mi = -__builtin_inff();   // running max for q = w*16+lr (dup across kg)
  float li = 0.f;                 // running sum for q = w*16+lr

  for (int kt = 0; kt < 8; kt++) {
    WRITEKV();
    if (kt < 7) LOADKV(kt + 1);
    __syncthreads();

    // S^T = K Q^T: lane holds S[q=w*16+lr][k=j*16+kg*4+rg]
    f32x4 s[4];
#pragma unroll
    for (int j = 0; j < 4; j++) {
      bf16x8 ak0 = *(const bf16x8*)(Ks + (j * 16 + lr) * LP + kg * 8);
      bf16x8 ak1 = *(const bf16x8*)(Ks + (j * 16 + lr) * LP + 32 + kg * 8);
      f32x4 z = {0.f, 0.f, 0.f, 0.f};
      z = MFMA16(ak0, bq0, z);
      z = MFMA16(ak1, bq1, z);
      s[j] = z;
    }

    // in-register row reduction (16 values) + 2 cross-group shfls
    f32x4 m4 = s[0];
#pragma unroll
    for (int j = 1; j < 4; j++)
#pragma unroll
      for (int rg = 0; rg < 4; rg++) m4[rg] = fmaxf(m4[rg], s[j][rg]);
    float mx = fmaxf(fmaxf(m4[0], m4[1]), fmaxf(m4[2], m4[3]));
    mx = fmaxf(mx, __shfl_xor(mx, 16));
    mx = fmaxf(mx, __shfl_xor(mx, 32));

    float mn = fmaxf(mi, mx);
    float alpha = __expf(mi - mn);
#pragma unroll
    for (int j = 0; j < 4; j++)
#pragma unroll
      for (int rg = 0; rg < 4; rg++) s[j][rg] = __expf(s[j][rg] - mn);
    f32x4 s4 = s[0];
#pragma unroll
    for (int j = 1; j < 4; j++)
#pragma unroll
      for (int rg = 0; rg < 4; rg++) s4[rg] += s[j][rg];
    float rs = (s4[0] + s4[1]) + (s4[2] + s4[3]);
    rs += __shfl_xor(rs, 16);
    rs += __shfl_xor(rs, 32);
    li = li * alpha + rs;
    mi = mn;

    // packed P write: rg are consecutive k -> u16x4 per j
#pragma unroll
    for (int j = 0; j < 4; j++) {
      u16x4 pv4 = {f2b(s[j][0]), f2b(s[j][1]), f2b(s[j][2]), f2b(s[j][3])};
      *(u16x4*)(Ps + (w * 16 + lr) * LP + j * 16 + kg * 4) = pv4;
    }

    // broadcast alpha (per q=lr) to O-layout rows (q=kg*4+rg)
    if (kg == 0) Al[w][lr] = alpha;
    f32x4 av = *(const f32x4*)&Al[w][kg * 4];
#pragma unroll
    for (int sb = 0; sb < 4; sb++)
#pragma unroll
      for (int rg = 0; rg < 4; rg++) O[sb][rg] *= av[rg];

    // PV (forward): A = P rows, B = V^T rows
    bf16x8 ap0 = *(const bf16x8*)(Ps + (w * 16 + lr) * LP + kg * 8);
    bf16x8 ap1 = *(const bf16x8*)(Ps + (w * 16 + lr) * LP + 32 + kg * 8);
#pragma unroll
    for (int sb = 0; sb < 4; sb++) {
      bf16x8 bv0 = *(const bf16x8*)(Vs + (sb * 16 + lr) * LP + kg * 8);
      bf16x8 bv1 = *(const bf16x8*)(Vs + (sb * 16 + lr) * LP + 32 + kg * 8);
      O[sb] = MFMA16(ap0, bv0, O[sb]);
      O[sb] = MFMA16(ap1, bv1, O[sb]);
    }
    __syncthreads();               // Ks/Vs reads done before next WRITEKV
  }

  // broadcast final li to O-layout rows
  if (kg == 0) Al[w][lr] = li;
  f32x4 lv = *(const f32x4*)&Al[w][kg * 4];

#pragma unroll
  for (int rg = 0; rg < 4; rg++) {
    float inv = 1.f / lv[rg];
    int t = qt * 64 + w * 16 + kg * 4 + rg;
    size_t rowbase = ((size_t)b * 512 + t) * 512;
#pragma unroll
    for (int sb = 0; sb < 4; sb++) {
      int hd = sb * 16 + lr;
      if (hd < 50)
        att[rowbase + h * 50 + hd] = f2b(O[sb][rg] * inv);
      else if (h == 9 && hd < 62)
        att[rowbase + 450 + hd] = 0;   // zero att pad cols 500..511
    }
  }
}

// ---------------- workspace layout (~114 MiB of the ~268 MiB ws) ----------------
static constexpr size_t MB = 1024 * 1024;
static constexpr size_t OFF_S0  = 0;                      // [0,16M)    x0 / out3 (bf16)
static constexpr size_t OFF_S1  = 16 * MB;                // [16M,32M)  ping-pong, then ATT
static constexpr size_t OFF_R   = 32 * MB;                // [32M,48M)  DW scratch -> OUT4
static constexpr size_t OFF_QKV = 48 * MB;                // [48M,108M) full head-separated QKV (60 MB)
static constexpr size_t OFF_PE  = 108 * MB;               // f32[512*512] (1 MB)
static constexpr size_t OFF_PW  = 109 * MB;
static constexpr size_t SZ_W = (size_t)512 * 512 * 2;
static constexpr size_t OFF_OW = OFF_PW + 4 * SZ_W;
static constexpr size_t OFF_FW = OFF_OW + SZ_W;
static constexpr size_t OFF_INW = OFF_FW + SZ_W;
static constexpr size_t OFF_INB = OFF_INW + (size_t)1536 * 512 * 2;   // f32[1536]

extern "C" void kernel_launch(void* const* d_in, const int* in_sizes, int n_in,
                              void* d_out, int out_size, void* d_ws, size_t ws_size,
                              hipStream_t stream) {
  const int* ori = (const int*)d_in[0];
  const float* x = (const float*)d_in[1];
  const float* dwv[4] = {(const float*)d_in[3], (const float*)d_in[7], (const float*)d_in[11], (const float*)d_in[15]};
  const float* dbv[4] = {(const float*)d_in[4], (const float*)d_in[8], (const float*)d_in[12], (const float*)d_in[16]};
  const float* pwv[4] = {(const float*)d_in[5], (const float*)d_in[9], (const float*)d_in[13], (const float*)d_in[17]};
  const float* pbv[4] = {(const float*)d_in[6], (const float*)d_in[10], (const float*)d_in[14], (const float*)d_in[18]};
  const float* in_w = (const float*)d_in[19];
  const float* in_b = (const float*)d_in[20];
  const float* out_w = (const float*)d_in[21];
  const float* out_b = (const float*)d_in[22];
  const float* ffc_w = (const float*)d_in[23];
  const float* ffc_b = (const float*)d_in[24];

  char* ws = (char*)d_ws;
  u16* S0  = (u16*)(ws + OFF_S0);
  u16* S1  = (u16*)(ws + OFF_S1);
  u16* R   = (u16*)(ws + OFF_R);
  u16* QKV = (u16*)(ws + OFF_QKV);
  float* PE = (float*)(ws + OFF_PE);
  u16* PW  = (u16*)(ws + OFF_PW);
  u16* OW  = (u16*)(ws + OFF_OW);
  u16* FW  = (u16*)(ws + OFF_FW);
  u16* INW = (u16*)(ws + OFF_INW);
  float* INB = (float*)(ws + OFF_INB);

  // all weight packing + PE table in one launch
  packall<<<5126, 256, 0, stream>>>(pwv[0], pwv[1], pwv[2], pwv[3], out_w, ffc_w, in_w, in_b,
                                    PW, OW, FW, INW, INB, PE);

  // x0 = pos_emb + x (table lookup)
  posemb<<<M, 256, 0, stream>>>(ori, x, PE, S0);

  // 4x sepconv + residual (DW scratch in R)
  u16* cur = S0;
  u16* nxt = S1;
  for (int i = 0; i < 4; i++) {
    dwconv<<<dim3(64, 32), 256, 0, stream>>>(cur, dwv[i], dbv[i], R);
    gemm_bt<<<dim3(128, 4), 256, 0, stream>>>(R, PW + (size_t)i * 512 * 512, pbv[i], 500,
                                              cur, nxt, nullptr, 512, 512);
    u16* t2 = cur; cur = nxt; nxt = t2;
  }
  // cur == S0 holds out3; S1 free

  // qkv projection (full batch) + attention (full batch, XCD-aware grid); ATT = S1
  gemm_qkv<<<dim3(128, 12), 256, 0, stream>>>(cur, INW, INB, QKV);
  attn<<<dim3(2560), 256, 0, stream>>>(QKV, S1);

  // out_proj + residual(out3=S0) -> OUT4 in R
  gemm_bt<<<dim3(128, 4), 256, 0, stream>>>(S1, OW, out_b, 500, cur, R, nullptr, 512, 512);

  // ffc + residual(OUT4) -> d_out f32 [M][500]
  gemm_bt<<<dim3(128, 4), 256, 0, stream>>>(R, FW, ffc_b, 500, R, nullptr, (float*)d_out, 500, 500);
}